// Round 13
// baseline (212.838 us; speedup 1.0000x reference)
//
#include <hip/hip_runtime.h>
#include <math.h>

#define BATCH 2
#define SEQLEN 1024
#define DMODEL 1024
#define DINNER 2048
#define NHEADS 32
#define HEADDIM 64
#define DSTATE 64
#define NTOK (BATCH * SEQLEN)                 // 2048
#define OUT_ELEMS (BATCH * SEQLEN * DMODEL)   // 2097152
#define NCHUNK 16                             // chunks per sequence (Q=64)
#define LDP 72                                // padded LDS stride (bf16 elems)
#define BCN 4128                              // fused B|C|dt projection width
#define BCLD 4128                             // BCb row stride

typedef unsigned short bf16u;
typedef __attribute__((ext_vector_type(8))) short short8;
typedef __attribute__((ext_vector_type(4))) float f32x4;

__device__ __forceinline__ float b2f(short u) {
  return __uint_as_float(((unsigned)(unsigned short)u) << 16);
}
__device__ __forceinline__ unsigned short f2b(float f) {
  unsigned u = __float_as_uint(f);
  u += 0x7fff + ((u >> 16) & 1);   // RNE
  return (unsigned short)(u >> 16);
}

__device__ __forceinline__ void gload16(const void* g, void* l) {
  __builtin_amdgcn_global_load_lds(
      (const __attribute__((address_space(1))) unsigned int*)g,
      (__attribute__((address_space(3))) unsigned int*)l, 16, 0, 0);
}

__device__ __forceinline__ void stv(float* p, float v) { *p = v; }
__device__ __forceinline__ void stv(bf16u* p, float v) { *p = f2b(v); }

// ---------------------------------------------------------------------------
// Fused f32 -> bf16 conversion of all weights + hidden, one launch.
// Segments (elems): hidden 2M | in_proj 4M | B_w 4M | C_w 4M | out_proj 2M |
// dt_w 64K (dt lands at wBCb elem offset 8M = row 4096 of fused BC weight).
// ---------------------------------------------------------------------------
__global__ __launch_bounds__(256) void cvt_all(
    const float* __restrict__ s0, bf16u* __restrict__ d0,
    const float* __restrict__ s1, bf16u* __restrict__ d1,
    const float* __restrict__ s2, bf16u* __restrict__ d2,
    const float* __restrict__ s3, bf16u* __restrict__ d3,
    const float* __restrict__ s4, bf16u* __restrict__ d4,
    const float* __restrict__ s5, bf16u* __restrict__ d5) {
  const size_t M1 = 1u << 20;
  size_t i = (size_t)(blockIdx.x * 256 + threadIdx.x) * 8;
  const float* src; bf16u* dst; size_t off;
  if (i < 2 * M1)       { src = s0; dst = d0; off = i; }
  else if (i < 6 * M1)  { src = s1; dst = d1; off = i - 2 * M1; }
  else if (i < 10 * M1) { src = s2; dst = d2; off = i - 6 * M1; }
  else if (i < 14 * M1) { src = s3; dst = d3; off = i - 10 * M1; }
  else if (i < 16 * M1) { src = s4; dst = d4; off = i - 14 * M1; }
  else if (i < 16 * M1 + 65536) { src = s5; dst = d5; off = i - 16 * M1; }
  else return;
  const float4 a = *(const float4*)(src + off);
  const float4 b = *(const float4*)(src + off + 4);
  short8 o;
  o[0] = f2b(a.x); o[1] = f2b(a.y); o[2] = f2b(a.z); o[3] = f2b(a.w);
  o[4] = f2b(b.x); o[5] = f2b(b.y); o[6] = f2b(b.z); o[7] = f2b(b.w);
  *(short8*)(dst + off) = o;
}

// ---------------------------------------------------------------------------
// zero out[0..n) (f32), float4 per thread
// ---------------------------------------------------------------------------
__global__ __launch_bounds__(256) void zero_f32(float* __restrict__ o, int n) {
  const int i = (blockIdx.x * 256 + threadIdx.x) * 4;
  if (i >= n) return;
  *(float4*)(o + i) = make_float4(0.f, 0.f, 0.f, 0.f);
}

// ---------------------------------------------------------------------------
// bf16 MFMA GEMM (r10-proven config):  C[m,n] = sum_k A[m][k+kbase]*B[n][k+kbase]
// Tile 128x64, BK=32, 256 threads (2x2 waves of 64x32), 36KB ring-3 LDS
// (4 blocks/CU). Single barrier/iter, reads-before-barrier, counted vmcnt
// distance-1. T1 XCD-chunked swizzle, M-fastest decode. grid.z = split-K
// slices. ATOMIC=true: slices atomicAdd into C (2-way commutative -> exact
// determinism); else writes C + z*zstrideC.
// ---------------------------------------------------------------------------
template <bool ATOMIC, typename OutT>
__global__ __launch_bounds__(256) void gemm_mfma(
    const bf16u* __restrict__ A, const bf16u* __restrict__ B,
    OutT* __restrict__ C, int M, int N, int Ksub, int lda, int ldb,
    size_t zstrideC) {
  __shared__ bf16u sA[3][128 * 32];   // 8KB / buffer
  __shared__ bf16u sB[3][64 * 32];    // 4KB / buffer
  const int t = threadIdx.x;
  const int lane = t & 63, wave = t >> 6;
  // T1 swizzle (requires nwg % 8 == 0)
  const int nwg = gridDim.x * gridDim.y;
  const int fid = blockIdx.y * gridDim.x + blockIdx.x;
  const int tile = (fid & 7) * (nwg >> 3) + (fid >> 3);
  const int bm = (tile % gridDim.y) * 128;
  const int bn = (tile / gridDim.y) * 64;
  const int wr = wave >> 1, wc = wave & 1;
  const int kbase = blockIdx.z * Ksub;
  OutT* Cz = C + (size_t)blockIdx.z * zstrideC;

  const int ra0 = bm + (t >> 2), ra1 = bm + 64 + (t >> 2);
  int rb0 = bn + (t >> 2);
  rb0 = rb0 < N ? rb0 : N - 1;
  const int kc = (((t & 3) ^ ((t >> 4) & 3))) * 8;

  const bf16u* Ap0 = A + (size_t)ra0 * lda + kbase + kc;
  const bf16u* Ap1 = A + (size_t)ra1 * lda + kbase + kc;
  const bf16u* Bp0 = B + (size_t)rb0 * ldb + kbase + kc;
  const int ldsoff = (wave * 64) * 8;

#define STAGE(buf, k0)                                   \
  do {                                                   \
    gload16(Ap0 + (k0), sA[buf] + ldsoff);               \
    gload16(Ap1 + (k0), sA[buf] + 2048 + ldsoff);        \
    gload16(Bp0 + (k0), sB[buf] + ldsoff);               \
  } while (0)

  const f32x4 zero = {0.f, 0.f, 0.f, 0.f};
  f32x4 acc[4][2];
#pragma unroll
  for (int m = 0; m < 4; ++m)
#pragma unroll
    for (int n = 0; n < 2; ++n) acc[m][n] = zero;

  const int ln15 = lane & 15, kq = lane >> 4;
  const int kswz = ((kq ^ ((ln15 >> 2) & 3))) * 8;
  const int nt = Ksub >> 5;

  STAGE(0, 0);
  STAGE(1, 32);
  int curb = 0;
  for (int it = 0; it < nt; ++it) {
    if (it + 2 < nt) {
      const int nb = (it + 2) % 3;
      STAGE(nb, (it + 2) * 32);
      asm volatile("s_waitcnt vmcnt(3)" ::: "memory");
    } else {
      asm volatile("s_waitcnt vmcnt(0)" ::: "memory");
    }
    const bf16u* pA = sA[curb];
    const bf16u* pB = sB[curb];
    short8 af[4], bfr[2];
#pragma unroll
    for (int m = 0; m < 4; ++m)
      af[m] = *(const short8*)&pA[(wr * 64 + m * 16 + ln15) * 32 + kswz];
#pragma unroll
    for (int n = 0; n < 2; ++n)
      bfr[n] = *(const short8*)&pB[(wc * 32 + n * 16 + ln15) * 32 + kswz];
    asm volatile("s_waitcnt lgkmcnt(0)" ::: "memory");
    __builtin_amdgcn_sched_barrier(0);
    __builtin_amdgcn_s_barrier();
    __builtin_amdgcn_s_setprio(1);
#pragma unroll
    for (int m = 0; m < 4; ++m)
#pragma unroll
      for (int n = 0; n < 2; ++n)
        acc[m][n] = __builtin_amdgcn_mfma_f32_16x16x32_bf16(af[m], bfr[n], acc[m][n], 0, 0, 0);
    __builtin_amdgcn_s_setprio(0);
    curb = (curb == 2) ? 0 : curb + 1;
  }
#undef STAGE

  const int rbase = bm + wr * 64, cbase = bn + wc * 32;
#pragma unroll
  for (int m = 0; m < 4; ++m) {
#pragma unroll
    for (int n = 0; n < 2; ++n) {
      const int col = cbase + n * 16 + ln15;
      if (col < N) {
#pragma unroll
        for (int r = 0; r < 4; ++r) {
          const int row = rbase + m * 16 + kq * 4 + r;
          if constexpr (ATOMIC)
            atomicAdd(&Cz[(size_t)row * N + col], acc[m][n][r]);
          else
            stv(&Cz[(size_t)row * N + col], acc[m][n][r]);
        }
      }
    }
  }
}

// ---------------------------------------------------------------------------
// Depthwise causal conv (width 4) + bias + SiLU. bf16 in/out.
// ---------------------------------------------------------------------------
__global__ __launch_bounds__(256) void conv_silu(
    const bf16u* __restrict__ xzb, const float* __restrict__ cw,
    const float* __restrict__ cb, bf16u* __restrict__ xcb) {
  const int i = blockIdx.x * 256 + threadIdx.x;  // 0..512K
  const int c8 = (i & 255) * 8;
  const int tok = i >> 8;
  const int l = tok & (SEQLEN - 1);
  const bf16u* xp = xzb + (size_t)tok * (2 * DINNER) + c8;
  const short8 zer = {0, 0, 0, 0, 0, 0, 0, 0};
  const short8 x0 = *(const short8*)xp;
  const short8 x1 = (l >= 1) ? *(const short8*)(xp - 1 * (2 * DINNER)) : zer;
  const short8 x2 = (l >= 2) ? *(const short8*)(xp - 2 * (2 * DINNER)) : zer;
  const short8 x3 = (l >= 3) ? *(const short8*)(xp - 3 * (2 * DINNER)) : zer;
  short8 ob;
#pragma unroll
  for (int j = 0; j < 8; ++j) {
    const float4 w = *(const float4*)(cw + (c8 + j) * 4);
    float acc = cb[c8 + j] + w.w * b2f(x0[j]);
    acc += w.z * b2f(x1[j]);
    acc += w.y * b2f(x2[j]);
    acc += w.x * b2f(x3[j]);
    const float s = acc / (1.f + __expf(-acc));
    ob[j] = (short)f2b(s);
  }
  *(short8*)(xcb + (size_t)tok * DINNER + c8) = ob;
}

// ---------------------------------------------------------------------------
// Chunked SSD, stage 1 (per chunk): dt softplus (dt_raw read from BCb col
// 4096+h, bf16), decay cumsum, G=C@B^T masked -> P, Y_intra = P@X (bf16 out),
// S = X^T diag(w) B. One block per (b,h,c).
// BCb rows [NTOK] x 4128: cols [0,2048)=B, [2048,4096)=C, [4096,4128)=dt_raw.
// ---------------------------------------------------------------------------
__global__ __launch_bounds__(256) void chunk_intra(
    const bf16u* __restrict__ xcb, const bf16u* __restrict__ BCb,
    const float* __restrict__ dt_b, const float* __restrict__ A_log,
    bf16u* __restrict__ ybb, float* __restrict__ Sbuf,
    float* __restrict__ rbuf, float* __restrict__ lambuf) {
  __shared__ bf16u sC[64 * LDP], sB[64 * LDP], sXT[64 * LDP];
  __shared__ bf16u sWBT[64 * LDP], sP[64 * LDP];
  __shared__ float sS[64], sDt[64], sW[64];

  const int blk = blockIdx.x;
  const int bh = blk >> 4, c = blk & (NCHUNK - 1);
  const int b = bh >> 5, h = bh & (NHEADS - 1);
  const int t = threadIdx.x, lane = t & 63, wave = t >> 6;
  const int t0 = b * SEQLEN + c * 64;
  const size_t rowbase = (size_t)t0 * DINNER + h * 64;        // x
  const size_t rowBC = (size_t)t0 * BCLD + h * 64;            // fused B/C

  // ---- P0: staging + dt softplus + decay scan ----
  if (wave == 0) {
    const float dr =
        b2f((short)BCb[(size_t)(t0 + lane) * BCLD + 4096 + h]) + dt_b[h];
    const float dtv = (dr > 20.f) ? dr : log1pf(__expf(dr));
    const float Ah = -__expf(A_log[h]);
    float s = Ah * dtv;
#pragma unroll
    for (int off = 1; off < 64; off <<= 1) {
      const float o = __shfl_up(s, off);
      if (lane >= off) s += o;
    }
    const float stot = __shfl(s, 63);
    sS[lane] = s;
    sDt[lane] = dtv;
    sW[lane] = __expf(stot - s) * dtv;
    rbuf[(size_t)blk * 64 + lane] = __expf(s);
    if (lane == 0) lambuf[blk] = __expf(stot);
  } else if (wave == 1) {
#pragma unroll
    for (int it = 0; it < 8; ++it) {
      const int slot = it * 64 + lane;
      const int r = slot >> 3, c8 = (slot & 7) * 8;
      *(short8*)&sC[r * LDP + c8] =
          *(const short8*)&BCb[rowBC + 2048 + (size_t)r * BCLD + c8];
    }
  } else if (wave == 2) {
#pragma unroll
    for (int it = 0; it < 8; ++it) {
      const int slot = it * 64 + lane;
      const int r = slot >> 3, c8 = (slot & 7) * 8;
      *(short8*)&sB[r * LDP + c8] =
          *(const short8*)&BCb[rowBC + (size_t)r * BCLD + c8];
    }
  } else {
#pragma unroll
    for (int it = 0; it < 8; ++it) {
      const int slot = it * 64 + lane;
      const int j = slot >> 3, p0 = (slot & 7) * 8;
      const short8 v = *(const short8*)&xcb[rowbase + (size_t)j * DINNER + p0];
#pragma unroll
      for (int k = 0; k < 8; ++k) sXT[(p0 + k) * LDP + j] = v[k];
    }
  }
  __syncthreads();

  // ---- P1: WBT[n][j] = w_j * B[j][n]; G mfma + mask -> P ----
  {
    const int j = t >> 2, n0 = (t & 3) * 16;
    const float wj = sW[j];
#pragma unroll
    for (int k = 0; k < 16; ++k)
      sWBT[(n0 + k) * LDP + j] = f2b(wj * b2f(sB[j * LDP + n0 + k]));
  }
  const int ln15 = lane & 15, kq = lane >> 4;
  const int i0 = wave * 16;
  const f32x4 zero = {0.f, 0.f, 0.f, 0.f};
  {
    f32x4 g[4];
#pragma unroll
    for (int jf = 0; jf < 4; ++jf) g[jf] = zero;
#pragma unroll
    for (int k0 = 0; k0 < 64; k0 += 32) {
      const short8 a = *(const short8*)&sC[(i0 + ln15) * LDP + k0 + kq * 8];
#pragma unroll
      for (int jf = 0; jf < 4; ++jf) {
        const short8 bb = *(const short8*)&sB[(jf * 16 + ln15) * LDP + k0 + kq * 8];
        g[jf] = __builtin_amdgcn_mfma_f32_16x16x32_bf16(a, bb, g[jf], 0, 0, 0);
      }
    }
#pragma unroll
    for (int jf = 0; jf < 4; ++jf) {
      const int j = jf * 16 + ln15;
      const float sj = sS[j], dtj = sDt[j];
#pragma unroll
      for (int r = 0; r < 4; ++r) {
        const int i = i0 + kq * 4 + r;
        const float v = (j <= i) ? g[jf][r] * __expf(sS[i] - sj) * dtj : 0.f;
        sP[i * LDP + j] = f2b(v);
      }
    }
  }
  __syncthreads();

  // ---- P2: Y_intra = P @ XT^T ; S = XT @ WBT^T ----
  f32x4 yi[4], ss[4];
#pragma unroll
  for (int f = 0; f < 4; ++f) { yi[f] = zero; ss[f] = zero; }
#pragma unroll
  for (int k0 = 0; k0 < 64; k0 += 32) {
    const short8 ap = *(const short8*)&sP[(i0 + ln15) * LDP + k0 + kq * 8];
    const short8 ax = *(const short8*)&sXT[(i0 + ln15) * LDP + k0 + kq * 8];
#pragma unroll
    for (int f = 0; f < 4; ++f) {
      const short8 bx = *(const short8*)&sXT[(f * 16 + ln15) * LDP + k0 + kq * 8];
      const short8 bw = *(const short8*)&sWBT[(f * 16 + ln15) * LDP + k0 + kq * 8];
      yi[f] = __builtin_amdgcn_mfma_f32_16x16x32_bf16(ap, bx, yi[f], 0, 0, 0);
      ss[f] = __builtin_amdgcn_mfma_f32_16x16x32_bf16(ax, bw, ss[f], 0, 0, 0);
    }
  }
  bf16u* yb = ybb + (size_t)blk * 4096;
  float* sb = Sbuf + (size_t)blk * 4096;
#pragma unroll
  for (int f = 0; f < 4; ++f) {
#pragma unroll
    for (int r = 0; r < 4; ++r) {
      const int row = i0 + kq * 4 + r;
      const int col = f * 16 + ln15;
      yb[row * 64 + col] = f2b(yi[f][r]);
      sb[row * 64 + col] = ss[f][r];
    }
  }
}

// ---------------------------------------------------------------------------
// Chunked SSD, stage 2: inter-chunk state scan (16 steps, scalar decay).
// ---------------------------------------------------------------------------
__global__ __launch_bounds__(256) void chunk_scan(
    const float* __restrict__ Sbuf, const float* __restrict__ lambuf,
    bf16u* __restrict__ Hprevb, float* __restrict__ hf) {
  const int bh = blockIdx.x;
  const int t = threadIdx.x;
  const int e0 = t * 16;
  float H[16];
#pragma unroll
  for (int j = 0; j < 16; ++j) H[j] = 0.f;

  float4 cur[4];
  float lam;
  {
    const float4* sp = (const float4*)(Sbuf + (size_t)(bh * NCHUNK) * 4096 + e0);
#pragma unroll
    for (int q = 0; q < 4; ++q) cur[q] = sp[q];
    lam = lambuf[bh * NCHUNK];
  }
  for (int c = 0; c < NCHUNK; ++c) {
    float4 nxt[4];
    float lamn = 0.f;
    if (c < NCHUNK - 1) {
      const float4* sp = (const float4*)(Sbuf + (size_t)(bh * NCHUNK + c + 1) * 4096 + e0);
#pragma unroll
      for (int q = 0; q < 4; ++q) nxt[q] = sp[q];
      lamn = lambuf[bh * NCHUNK + c + 1];
    }
    short8 o0, o1;
#pragma unroll
    for (int j = 0; j < 8; ++j) o0[j] = (short)f2b(H[j]);
#pragma unroll
    for (int j = 0; j < 8; ++j) o1[j] = (short)f2b(H[8 + j]);
    *(short8*)&Hprevb[(size_t)(bh * NCHUNK + c) * 4096 + e0] = o0;
    *(short8*)&Hprevb[(size_t)(bh * NCHUNK + c) * 4096 + e0 + 8] = o1;
#pragma unroll
    for (int q = 0; q < 4; ++q) {
      H[q * 4 + 0] = lam * H[q * 4 + 0] + cur[q].x;
      H[q * 4 + 1] = lam * H[q * 4 + 1] + cur[q].y;
      H[q * 4 + 2] = lam * H[q * 4 + 2] + cur[q].z;
      H[q * 4 + 3] = lam * H[q * 4 + 3] + cur[q].w;
    }
#pragma unroll
    for (int q = 0; q < 4; ++q) cur[q] = nxt[q];
    lam = lamn;
  }
  float* hp = hf + (size_t)bh * 4096 + e0;
#pragma unroll
  for (int q = 0; q < 4; ++q)
    *(float4*)(hp + q * 4) =
        make_float4(H[q * 4], H[q * 4 + 1], H[q * 4 + 2], H[q * 4 + 3]);
}

// ---------------------------------------------------------------------------
// Chunked SSD, stage 3 (per chunk): Y = Y_intra + r_i * C @ Hprev^T + D*x.
// ---------------------------------------------------------------------------
__global__ __launch_bounds__(256) void chunk_inter(
    const bf16u* __restrict__ BCb, const bf16u* __restrict__ Hprevb,
    const bf16u* __restrict__ xcb, const bf16u* __restrict__ ybb,
    const float* __restrict__ rbuf, const float* __restrict__ Dvec,
    bf16u* __restrict__ yout) {
  __shared__ bf16u sC[64 * LDP], sH[64 * LDP];
  __shared__ float sR[64];
  const int blk = blockIdx.x;
  const int bh = blk >> 4, c = blk & (NCHUNK - 1);
  const int b = bh >> 5, h = bh & (NHEADS - 1);
  const int t = threadIdx.x, lane = t & 63, wave = t >> 6;
  const int t0 = b * SEQLEN + c * 64;
  const size_t rowbase = (size_t)t0 * DINNER + h * 64;
  const size_t rowBC = (size_t)t0 * BCLD + h * 64;

#pragma unroll
  for (int it = 0; it < 2; ++it) {
    const int slot = it * 256 + t;          // 0..511
    const int r = slot >> 3, c8 = (slot & 7) * 8;
    *(short8*)&sC[r * LDP + c8] =
        *(const short8*)&BCb[rowBC + 2048 + (size_t)r * BCLD + c8];
    *(short8*)&sH[r * LDP + c8] =
        *(const short8*)&Hprevb[(size_t)blk * 4096 + slot * 8];
  }
  if (t < 64) sR[t] = rbuf[(size_t)blk * 64 + t];
  __syncthreads();

  const int ln15 = lane & 15, kq = lane >> 4;
  const int i0 = wave * 16;
  const f32x4 zero = {0.f, 0.f, 0.f, 0.f};
  f32x4 acc[4];
#pragma unroll
  for (int f = 0; f < 4; ++f) acc[f] = zero;
#pragma unroll
  for (int k0 = 0; k0 < 64; k0 += 32) {
    const short8 a = *(const short8*)&sC[(i0 + ln15) * LDP + k0 + kq * 8];
#pragma unroll
    for (int f = 0; f < 4; ++f) {
      const short8 bh8 = *(const short8*)&sH[(f * 16 + ln15) * LDP + k0 + kq * 8];
      acc[f] = __builtin_amdgcn_mfma_f32_16x16x32_bf16(a, bh8, acc[f], 0, 0, 0);
    }
  }
  const float Dh = Dvec[h];
  const bf16u* yb = ybb + (size_t)blk * 4096;
#pragma unroll
  for (int f = 0; f < 4; ++f) {
    const int p = f * 16 + ln15;
#pragma unroll
    for (int r = 0; r < 4; ++r) {
      const int i = i0 + kq * 4 + r;
      const float xv = b2f((short)xcb[rowbase + (size_t)i * DINNER + p]);
      const float y = b2f((short)yb[i * 64 + p]) + sR[i] * acc[f][r] + Dh * xv;
      yout[rowbase + (size_t)i * DINNER + p] = f2b(y);
    }
  }
}

// ---------------------------------------------------------------------------
// LayerNorm(2048) + SiLU(z) gate. bf16 y/z in, bf16 out. One block per token.
// ---------------------------------------------------------------------------
__global__ __launch_bounds__(256) void ln_gate(
    const bf16u* __restrict__ y, const bf16u* __restrict__ xzb,
    const float* __restrict__ lnw, const float* __restrict__ lnb,
    bf16u* __restrict__ out) {
  const int tok = blockIdx.x;
  const int t = threadIdx.x;
  const short8 yv8 = *(const short8*)(y + (size_t)tok * DINNER + t * 8);
  const short8 zv8 = *(const short8*)(xzb + (size_t)tok * (2 * DINNER) + DINNER + t * 8);
  float v[8];
  float s = 0.f, s2 = 0.f;
#pragma unroll
  for (int j = 0; j < 8; ++j) {
    v[j] = b2f(yv8[j]);
    s += v[j];
    s2 += v[j] * v[j];
  }
#pragma unroll
  for (int off = 32; off > 0; off >>= 1) {
    s += __shfl_down(s, off);
    s2 += __shfl_down(s2, off);
  }
  __shared__ float ws[4], ws2[4];
  const int wid = t >> 6;
  if ((t & 63) == 0) { ws[wid] = s; ws2[wid] = s2; }
  __syncthreads();
  const float mean = (ws[0] + ws[1] + ws[2] + ws[3]) * (1.f / DINNER);
  const float m2 = (ws2[0] + ws2[1] + ws2[2] + ws2[3]) * (1.f / DINNER);
  const float rstd = rsqrtf(m2 - mean * mean + 1e-5f);
  const float4 w0 = *(const float4*)(lnw + t * 8);
  const float4 w1 = *(const float4*)(lnw + t * 8 + 4);
  const float4 b0 = *(const float4*)(lnb + t * 8);
  const float4 b1 = *(const float4*)(lnb + t * 8 + 4);
  const float wv[8] = {w0.x, w0.y, w0.z, w0.w, w1.x, w1.y, w1.z, w1.w};
  const float bv[8] = {b0.x, b0.y, b0.z, b0.w, b1.x, b1.y, b1.z, b1.w};
  short8 o;
#pragma unroll
  for (int j = 0; j < 8; ++j) {
    const float zn = b2f(zv8[j]);
    const float gate = zn / (1.f + __expf(-zn));
    o[j] = (short)f2b(((v[j] - mean) * rstd * wv[j] + bv[j]) * gate);
  }
  *(short8*)(out + (size_t)tok * DINNER + t * 8) = o;
}

// ---------------------------------------------------------------------------
extern "C" void kernel_launch(void* const* d_in, const int* in_sizes, int n_in,
                              void* d_out, int out_size, void* d_ws, size_t ws_size,
                              hipStream_t stream) {
  const float* hidden = (const float*)d_in[0];
  const float* in_proj_w = (const float*)d_in[1];
  const float* conv_w = (const float*)d_in[2];
  const float* conv_b = (const float*)d_in[3];
  const float* A_log = (const float*)d_in[4];
  const float* dt_w = (const float*)d_in[5];
  const float* dt_b = (const float*)d_in[6];
  const float* B_w = (const float*)d_in[7];
  const float* C_w = (const float*)d_in[8];
  const float* Dv = (const float*)d_in[9];
  const float* ln_w = (const float*)d_in[10];
  const float* ln_b = (const float*)d_in[11];
  const float* out_proj_w = (const float*)d_in[12];

  float* out = (float*)d_out;
  float* f = (float*)d_ws;
  const size_t M1 = 1u << 20;

  // workspace layout (float-offset units):
  bf16u* xzb    = (bf16u*)(f + 0);              // [0,4M)    xz bf16 (8M elems)
  bf16u* xcb    = (bf16u*)(f + 4 * M1);         // [4M,6M)   conv out bf16
  bf16u* BCb    = (bf16u*)(f + 6 * M1);         // [6M,10.5M)  2048x4128 bf16
  bf16u* wBCb   = (bf16u*)(f + 10 * M1 + 524288);  // [10.5M,15M) 4128x2048 bf16 (dead after BC gemm)
  bf16u* ybb    = (bf16u*)(f + 10 * M1 + 524288);  // [10.5M,12.5M) y_intra (after wBCb dead)
  bf16u* ygb    = (bf16u*)(f + 12 * M1 + 524288);  // [12.5M,14.5M) (after wBCb dead)
  bf16u* wInb   = (bf16u*)(f + 15 * M1);        // [15M,17M)  (dead after in_proj)
  bf16u* hiddenb= (bf16u*)(f + 17 * M1);        // [17M,18M)  (dead after in_proj)
  float* Sbuf   = f + 15 * M1;                  // [15M,19M)  (after wInb/hiddenb dead)
  bf16u* yscb   = (bf16u*)(f + 15 * M1);        // [15M,17M)  (after chunk_scan read of Sbuf)
  bf16u* Hprevb = (bf16u*)(f + 19 * M1);        // [19M,21M)
  bf16u* wOb    = (bf16u*)(f + 21 * M1);        // [21M,22M)
  float* rbuf   = f + 22 * M1;                  // [22M,+64K)
  float* lambuf = f + 22 * M1 + 65536;          // [+1K]

  float* hf = out + OUT_ELEMS;

  // 0. all f32->bf16 conversions in ONE launch (dt_w -> rows 4096.. of wBCb)
  cvt_all<<<8224, 256, 0, stream>>>(hidden, hiddenb, in_proj_w, wInb,
                                    B_w, wBCb, C_w, wBCb + 4 * M1,
                                    out_proj_w, wOb, dt_w, wBCb + 8 * M1);
  // 0b. zero d_out (atomic split-K accumulates into it)
  zero_f32<<<2048, 256, 0, stream>>>(out, OUT_ELEMS);

  // 1. xz = hidden @ in_proj_w^T  [2048 x 4096], K=1024  (bf16 out)
  gemm_mfma<false, bf16u><<<dim3(64, 16, 1), 256, 0, stream>>>(
      hiddenb, wInb, xzb, NTOK, 2 * DINNER, DMODEL, DMODEL, DMODEL, 0);
  // 2. conv + SiLU -> xcb (bf16)
  conv_silu<<<2048, 256, 0, stream>>>(xzb, conv_w, conv_b, xcb);
  // 3. fused B/C/dt projection: [2048 x 4128], K=2048 (bf16 out)
  gemm_mfma<false, bf16u><<<dim3(65, 16, 1), 256, 0, stream>>>(
      xcb, wBCb, BCb, NTOK, BCN, DINNER, DINNER, DINNER, 0);
  // 4. per-chunk intra + states (dt softplus fused in)
  chunk_intra<<<BATCH * NHEADS * NCHUNK, 256, 0, stream>>>(
      xcb, BCb, dt_b, A_log, ybb, Sbuf, rbuf, lambuf);
  // 5. inter-chunk scan (also writes h_final)
  chunk_scan<<<BATCH * NHEADS, 256, 0, stream>>>(Sbuf, lambuf, Hprevb, hf);
  // 6. combine -> y (bf16)
  chunk_inter<<<BATCH * NHEADS * NCHUNK, 256, 0, stream>>>(
      BCb, Hprevb, xcb, ybb, rbuf, Dv, yscb);
  // 7. LN + gate -> ygb (bf16)
  ln_gate<<<NTOK, 256, 0, stream>>>(yscb, xzb, ln_w, ln_b, ygb);
  // 8. out += yg @ out_proj_w^T  [2048 x 1024], K=2048, split-K=2 atomic
  gemm_mfma<true, float><<<dim3(16, 16, 2), 256, 0, stream>>>(
      ygb, wOb, out, NTOK, DMODEL, DINNER / 2, DINNER, DINNER, 0);
}

// Round 15
// 185.496 us; speedup vs baseline: 1.1474x; 1.1474x over previous
//
#include <hip/hip_runtime.h>
#include <math.h>

#define BATCH 2
#define SEQLEN 1024
#define DMODEL 1024
#define DINNER 2048
#define NHEADS 32
#define HEADDIM 64
#define DSTATE 64
#define NTOK (BATCH * SEQLEN)                 // 2048
#define OUT_ELEMS (BATCH * SEQLEN * DMODEL)   // 2097152
#define NCHUNK 16                             // chunks per sequence (Q=64)
#define LDP 72                                // padded LDS stride (bf16 elems)

typedef unsigned short bf16u;
typedef __attribute__((ext_vector_type(8))) short short8;
typedef __attribute__((ext_vector_type(4))) float f32x4;

__device__ __forceinline__ float b2f(short u) {
  return __uint_as_float(((unsigned)(unsigned short)u) << 16);
}
__device__ __forceinline__ unsigned short f2b(float f) {
  unsigned u = __float_as_uint(f);
  u += 0x7fff + ((u >> 16) & 1);   // RNE
  return (unsigned short)(u >> 16);
}

__device__ __forceinline__ void gload16(const void* g, void* l) {
  __builtin_amdgcn_global_load_lds(
      (const __attribute__((address_space(1))) unsigned int*)g,
      (__attribute__((address_space(3))) unsigned int*)l, 16, 0, 0);
}

__device__ __forceinline__ void stv(float* p, float v) { *p = v; }
__device__ __forceinline__ void stv(bf16u* p, float v) { *p = f2b(v); }

// ---------------------------------------------------------------------------
// Fused f32 -> bf16 conversion of all weights + hidden, one launch.
// ---------------------------------------------------------------------------
__global__ __launch_bounds__(256) void cvt_all(
    const float* __restrict__ s0, bf16u* __restrict__ d0,
    const float* __restrict__ s1, bf16u* __restrict__ d1,
    const float* __restrict__ s2, bf16u* __restrict__ d2,
    const float* __restrict__ s3, bf16u* __restrict__ d3,
    const float* __restrict__ s4, bf16u* __restrict__ d4,
    const float* __restrict__ s5, bf16u* __restrict__ d5) {
  const size_t M1 = 1u << 20;
  size_t i = (size_t)(blockIdx.x * 256 + threadIdx.x) * 8;
  const float* src; bf16u* dst; size_t off;
  if (i < 2 * M1)       { src = s0; dst = d0; off = i; }
  else if (i < 6 * M1)  { src = s1; dst = d1; off = i - 2 * M1; }
  else if (i < 10 * M1) { src = s2; dst = d2; off = i - 6 * M1; }
  else if (i < 14 * M1) { src = s3; dst = d3; off = i - 10 * M1; }
  else if (i < 16 * M1) { src = s4; dst = d4; off = i - 14 * M1; }
  else if (i < 16 * M1 + 65536) { src = s5; dst = d5; off = i - 16 * M1; }
  else return;
  const float4 a = *(const float4*)(src + off);
  const float4 b = *(const float4*)(src + off + 4);
  short8 o;
  o[0] = f2b(a.x); o[1] = f2b(a.y); o[2] = f2b(a.z); o[3] = f2b(a.w);
  o[4] = f2b(b.x); o[5] = f2b(b.y); o[6] = f2b(b.z); o[7] = f2b(b.w);
  *(short8*)(dst + off) = o;
}

// ---------------------------------------------------------------------------
// bf16 MFMA GEMM (r10-proven config):  C[m,n] = sum_k A[m][k+kbase]*B[n][k+kbase]
// Tile 128x64, BK=32, 256 threads (2x2 waves of 64x32), 36KB ring-3 LDS
// (4 blocks/CU). Single barrier/iter, reads-before-barrier, counted vmcnt
// distance-1. T1 XCD-chunked swizzle, M-fastest decode. grid.z = split-K
// slices; writes to C + z*zstrideC (plain stores only — deterministic).
// ---------------------------------------------------------------------------
template <typename OutT>
__global__ __launch_bounds__(256) void gemm_mfma(
    const bf16u* __restrict__ A, const bf16u* __restrict__ B,
    OutT* __restrict__ C, int M, int N, int Ksub, int lda, int ldb,
    size_t zstrideC) {
  __shared__ bf16u sA[3][128 * 32];   // 8KB / buffer
  __shared__ bf16u sB[3][64 * 32];    // 4KB / buffer
  const int t = threadIdx.x;
  const int lane = t & 63, wave = t >> 6;
  // T1 swizzle (requires nwg % 8 == 0)
  const int nwg = gridDim.x * gridDim.y;
  const int fid = blockIdx.y * gridDim.x + blockIdx.x;
  const int tile = (fid & 7) * (nwg >> 3) + (fid >> 3);
  const int bm = (tile % gridDim.y) * 128;
  const int bn = (tile / gridDim.y) * 64;
  const int wr = wave >> 1, wc = wave & 1;
  const int kbase = blockIdx.z * Ksub;
  OutT* Cz = C + (size_t)blockIdx.z * zstrideC;

  const int ra0 = bm + (t >> 2), ra1 = bm + 64 + (t >> 2);
  int rb0 = bn + (t >> 2);
  rb0 = rb0 < N ? rb0 : N - 1;
  const int kc = (((t & 3) ^ ((t >> 4) & 3))) * 8;

  const bf16u* Ap0 = A + (size_t)ra0 * lda + kbase + kc;
  const bf16u* Ap1 = A + (size_t)ra1 * lda + kbase + kc;
  const bf16u* Bp0 = B + (size_t)rb0 * ldb + kbase + kc;
  const int ldsoff = (wave * 64) * 8;

#define STAGE(buf, k0)                                   \
  do {                                                   \
    gload16(Ap0 + (k0), sA[buf] + ldsoff);               \
    gload16(Ap1 + (k0), sA[buf] + 2048 + ldsoff);        \
    gload16(Bp0 + (k0), sB[buf] + ldsoff);               \
  } while (0)

  const f32x4 zero = {0.f, 0.f, 0.f, 0.f};
  f32x4 acc[4][2];
#pragma unroll
  for (int m = 0; m < 4; ++m)
#pragma unroll
    for (int n = 0; n < 2; ++n) acc[m][n] = zero;

  const int ln15 = lane & 15, kq = lane >> 4;
  const int kswz = ((kq ^ ((ln15 >> 2) & 3))) * 8;
  const int nt = Ksub >> 5;

  STAGE(0, 0);
  STAGE(1, 32);
  int curb = 0;
  for (int it = 0; it < nt; ++it) {
    if (it + 2 < nt) {
      const int nb = (it + 2) % 3;
      STAGE(nb, (it + 2) * 32);
      asm volatile("s_waitcnt vmcnt(3)" ::: "memory");
    } else {
      asm volatile("s_waitcnt vmcnt(0)" ::: "memory");
    }
    const bf16u* pA = sA[curb];
    const bf16u* pB = sB[curb];
    short8 af[4], bfr[2];
#pragma unroll
    for (int m = 0; m < 4; ++m)
      af[m] = *(const short8*)&pA[(wr * 64 + m * 16 + ln15) * 32 + kswz];
#pragma unroll
    for (int n = 0; n < 2; ++n)
      bfr[n] = *(const short8*)&pB[(wc * 32 + n * 16 + ln15) * 32 + kswz];
    asm volatile("s_waitcnt lgkmcnt(0)" ::: "memory");
    __builtin_amdgcn_sched_barrier(0);
    __builtin_amdgcn_s_barrier();
    __builtin_amdgcn_s_setprio(1);
#pragma unroll
    for (int m = 0; m < 4; ++m)
#pragma unroll
      for (int n = 0; n < 2; ++n)
        acc[m][n] = __builtin_amdgcn_mfma_f32_16x16x32_bf16(af[m], bfr[n], acc[m][n], 0, 0, 0);
    __builtin_amdgcn_s_setprio(0);
    curb = (curb == 2) ? 0 : curb + 1;
  }
#undef STAGE

  const int rbase = bm + wr * 64, cbase = bn + wc * 32;
#pragma unroll
  for (int m = 0; m < 4; ++m) {
#pragma unroll
    for (int n = 0; n < 2; ++n) {
      const int col = cbase + n * 16 + ln15;
      if (col < N) {
#pragma unroll
        for (int r = 0; r < 4; ++r) {
          const int row = rbase + m * 16 + kq * 4 + r;
          stv(&Cz[(size_t)row * N + col], acc[m][n][r]);
        }
      }
    }
  }
}

// ---------------------------------------------------------------------------
// out = a + b (f32), 4 elems/thread
// ---------------------------------------------------------------------------
__global__ __launch_bounds__(256) void add_f32(const float* __restrict__ a,
                                               const float* __restrict__ b,
                                               float* __restrict__ o, int n) {
  const int i = (blockIdx.x * 256 + threadIdx.x) * 4;
  if (i >= n) return;
  const float4 x = *(const float4*)(a + i);
  const float4 y = *(const float4*)(b + i);
  *(float4*)(o + i) = make_float4(x.x + y.x, x.y + y.y, x.z + y.z, x.w + y.w);
}

// ---------------------------------------------------------------------------
// Depthwise causal conv (width 4) + bias + SiLU. bf16 in/out.
// ---------------------------------------------------------------------------
__global__ __launch_bounds__(256) void conv_silu(
    const bf16u* __restrict__ xzb, const float* __restrict__ cw,
    const float* __restrict__ cb, bf16u* __restrict__ xcb) {
  const int i = blockIdx.x * 256 + threadIdx.x;  // 0..512K
  const int c8 = (i & 255) * 8;
  const int tok = i >> 8;
  const int l = tok & (SEQLEN - 1);
  const bf16u* xp = xzb + (size_t)tok * (2 * DINNER) + c8;
  const short8 zer = {0, 0, 0, 0, 0, 0, 0, 0};
  const short8 x0 = *(const short8*)xp;
  const short8 x1 = (l >= 1) ? *(const short8*)(xp - 1 * (2 * DINNER)) : zer;
  const short8 x2 = (l >= 2) ? *(const short8*)(xp - 2 * (2 * DINNER)) : zer;
  const short8 x3 = (l >= 3) ? *(const short8*)(xp - 3 * (2 * DINNER)) : zer;
  short8 ob;
#pragma unroll
  for (int j = 0; j < 8; ++j) {
    const float4 w = *(const float4*)(cw + (c8 + j) * 4);
    float acc = cb[c8 + j] + w.w * b2f(x0[j]);
    acc += w.z * b2f(x1[j]);
    acc += w.y * b2f(x2[j]);
    acc += w.x * b2f(x3[j]);
    const float s = acc / (1.f + __expf(-acc));
    ob[j] = (short)f2b(s);
  }
  *(short8*)(xcb + (size_t)tok * DINNER + c8) = ob;
}

// ---------------------------------------------------------------------------
// Chunked SSD, stage 1 (per chunk): dt softplus (fused from 8 split-K
// partials), decay cumsum, G=C@B^T masked -> P, Y_intra = P@X (bf16 out),
// S = X^T diag(w) B. One block per (b,h,c).
// BCb [NTOK,4096]: cols [0,2048)=B, [2048,4096)=C.
// ---------------------------------------------------------------------------
__global__ __launch_bounds__(256) void chunk_intra(
    const bf16u* __restrict__ xcb, const bf16u* __restrict__ BCb,
    const float* __restrict__ dtp8, const float* __restrict__ dt_b,
    const float* __restrict__ A_log,
    bf16u* __restrict__ ybb, float* __restrict__ Sbuf,
    float* __restrict__ rbuf, float* __restrict__ lambuf) {
  __shared__ bf16u sC[64 * LDP], sB[64 * LDP], sXT[64 * LDP];
  __shared__ bf16u sWBT[64 * LDP], sP[64 * LDP];
  __shared__ float sS[64], sDt[64], sW[64];

  const int blk = blockIdx.x;
  const int bh = blk >> 4, c = blk & (NCHUNK - 1);
  const int b = bh >> 5, h = bh & (NHEADS - 1);
  const int t = threadIdx.x, lane = t & 63, wave = t >> 6;
  const int t0 = b * SEQLEN + c * 64;
  const size_t rowbase = (size_t)t0 * DINNER + h * 64;        // x
  const size_t rowBC = (size_t)t0 * 4096 + h * 64;            // fused B/C

  // ---- P0: staging + dt softplus + decay scan ----
  if (wave == 0) {
    const size_t di = (size_t)(t0 + lane) * NHEADS + h;
    float dr = dt_b[h];
#pragma unroll
    for (int k = 0; k < 8; ++k) dr += dtp8[di + (size_t)k * 65536];
    const float dtv = (dr > 20.f) ? dr : log1pf(__expf(dr));
    const float Ah = -__expf(A_log[h]);
    float s = Ah * dtv;
#pragma unroll
    for (int off = 1; off < 64; off <<= 1) {
      const float o = __shfl_up(s, off);
      if (lane >= off) s += o;
    }
    const float stot = __shfl(s, 63);
    sS[lane] = s;
    sDt[lane] = dtv;
    sW[lane] = __expf(stot - s) * dtv;
    rbuf[(size_t)blk * 64 + lane] = __expf(s);
    if (lane == 0) lambuf[blk] = __expf(stot);
  } else if (wave == 1) {
#pragma unroll
    for (int it = 0; it < 8; ++it) {
      const int slot = it * 64 + lane;
      const int r = slot >> 3, c8 = (slot & 7) * 8;
      *(short8*)&sC[r * LDP + c8] =
          *(const short8*)&BCb[rowBC + 2048 + (size_t)r * 4096 + c8];
    }
  } else if (wave == 2) {
#pragma unroll
    for (int it = 0; it < 8; ++it) {
      const int slot = it * 64 + lane;
      const int r = slot >> 3, c8 = (slot & 7) * 8;
      *(short8*)&sB[r * LDP + c8] =
          *(const short8*)&BCb[rowBC + (size_t)r * 4096 + c8];
    }
  } else {
#pragma unroll
    for (int it = 0; it < 8; ++it) {
      const int slot = it * 64 + lane;
      const int j = slot >> 3, p0 = (slot & 7) * 8;
      const short8 v = *(const short8*)&xcb[rowbase + (size_t)j * DINNER + p0];
#pragma unroll
      for (int k = 0; k < 8; ++k) sXT[(p0 + k) * LDP + j] = v[k];
    }
  }
  __syncthreads();

  // ---- P1: WBT[n][j] = w_j * B[j][n]; G mfma + mask -> P ----
  {
    const int j = t >> 2, n0 = (t & 3) * 16;
    const float wj = sW[j];
#pragma unroll
    for (int k = 0; k < 16; ++k)
      sWBT[(n0 + k) * LDP + j] = f2b(wj * b2f(sB[j * LDP + n0 + k]));
  }
  const int ln15 = lane & 15, kq = lane >> 4;
  const int i0 = wave * 16;
  const f32x4 zero = {0.f, 0.f, 0.f, 0.f};
  {
    f32x4 g[4];
#pragma unroll
    for (int jf = 0; jf < 4; ++jf) g[jf] = zero;
#pragma unroll
    for (int k0 = 0; k0 < 64; k0 += 32) {
      const short8 a = *(const short8*)&sC[(i0 + ln15) * LDP + k0 + kq * 8];
#pragma unroll
      for (int jf = 0; jf < 4; ++jf) {
        const short8 bb = *(const short8*)&sB[(jf * 16 + ln15) * LDP + k0 + kq * 8];
        g[jf] = __builtin_amdgcn_mfma_f32_16x16x32_bf16(a, bb, g[jf], 0, 0, 0);
      }
    }
#pragma unroll
    for (int jf = 0; jf < 4; ++jf) {
      const int j = jf * 16 + ln15;
      const float sj = sS[j], dtj = sDt[j];
#pragma unroll
      for (int r = 0; r < 4; ++r) {
        const int i = i0 + kq * 4 + r;
        const float v = (j <= i) ? g[jf][r] * __expf(sS[i] - sj) * dtj : 0.f;
        sP[i * LDP + j] = f2b(v);
      }
    }
  }
  __syncthreads();

  // ---- P2: Y_intra = P @ XT^T ; S = XT @ WBT^T ----
  f32x4 yi[4], ss[4];
#pragma unroll
  for (int f = 0; f < 4; ++f) { yi[f] = zero; ss[f] = zero; }
#pragma unroll
  for (int k0 = 0; k0 < 64; k0 += 32) {
    const short8 ap = *(const short8*)&sP[(i0 + ln15) * LDP + k0 + kq * 8];
    const short8 ax = *(const short8*)&sXT[(i0 + ln15) * LDP + k0 + kq * 8];
#pragma unroll
    for (int f = 0; f < 4; ++f) {
      const short8 bx = *(const short8*)&sXT[(f * 16 + ln15) * LDP + k0 + kq * 8];
      const short8 bw = *(const short8*)&sWBT[(f * 16 + ln15) * LDP + k0 + kq * 8];
      yi[f] = __builtin_amdgcn_mfma_f32_16x16x32_bf16(ap, bx, yi[f], 0, 0, 0);
      ss[f] = __builtin_amdgcn_mfma_f32_16x16x32_bf16(ax, bw, ss[f], 0, 0, 0);
    }
  }
  bf16u* yb = ybb + (size_t)blk * 4096;
  float* sb = Sbuf + (size_t)blk * 4096;
#pragma unroll
  for (int f = 0; f < 4; ++f) {
#pragma unroll
    for (int r = 0; r < 4; ++r) {
      const int row = i0 + kq * 4 + r;
      const int col = f * 16 + ln15;
      yb[row * 64 + col] = f2b(yi[f][r]);
      sb[row * 64 + col] = ss[f][r];
    }
  }
}

// ---------------------------------------------------------------------------
// Chunked SSD, stage 2: inter-chunk state scan (16 steps, scalar decay).
// ---------------------------------------------------------------------------
__global__ __launch_bounds__(256) void chunk_scan(
    const float* __restrict__ Sbuf, const float* __restrict__ lambuf,
    bf16u* __restrict__ Hprevb, float* __restrict__ hf) {
  const int bh = blockIdx.x;
  const int t = threadIdx.x;
  const int e0 = t * 16;
  float H[16];
#pragma unroll
  for (int j = 0; j < 16; ++j) H[j] = 0.f;

  float4 cur[4];
  float lam;
  {
    const float4* sp = (const float4*)(Sbuf + (size_t)(bh * NCHUNK) * 4096 + e0);
#pragma unroll
    for (int q = 0; q < 4; ++q) cur[q] = sp[q];
    lam = lambuf[bh * NCHUNK];
  }
  for (int c = 0; c < NCHUNK; ++c) {
    float4 nxt[4];
    float lamn = 0.f;
    if (c < NCHUNK - 1) {
      const float4* sp = (const float4*)(Sbuf + (size_t)(bh * NCHUNK + c + 1) * 4096 + e0);
#pragma unroll
      for (int q = 0; q < 4; ++q) nxt[q] = sp[q];
      lamn = lambuf[bh * NCHUNK + c + 1];
    }
    short8 o0, o1;
#pragma unroll
    for (int j = 0; j < 8; ++j) o0[j] = (short)f2b(H[j]);
#pragma unroll
    for (int j = 0; j < 8; ++j) o1[j] = (short)f2b(H[8 + j]);
    *(short8*)&Hprevb[(size_t)(bh * NCHUNK + c) * 4096 + e0] = o0;
    *(short8*)&Hprevb[(size_t)(bh * NCHUNK + c) * 4096 + e0 + 8] = o1;
#pragma unroll
    for (int q = 0; q < 4; ++q) {
      H[q * 4 + 0] = lam * H[q * 4 + 0] + cur[q].x;
      H[q * 4 + 1] = lam * H[q * 4 + 1] + cur[q].y;
      H[q * 4 + 2] = lam * H[q * 4 + 2] + cur[q].z;
      H[q * 4 + 3] = lam * H[q * 4 + 3] + cur[q].w;
    }
#pragma unroll
    for (int q = 0; q < 4; ++q) cur[q] = nxt[q];
    lam = lamn;
  }
  float* hp = hf + (size_t)bh * 4096 + e0;
#pragma unroll
  for (int q = 0; q < 4; ++q)
    *(float4*)(hp + q * 4) =
        make_float4(H[q * 4], H[q * 4 + 1], H[q * 4 + 2], H[q * 4 + 3]);
}

// ---------------------------------------------------------------------------
// Chunked SSD, stage 3 (per chunk): Y = Y_intra + r_i * C @ Hprev^T + D*x.
// ---------------------------------------------------------------------------
__global__ __launch_bounds__(256) void chunk_inter(
    const bf16u* __restrict__ BCb, const bf16u* __restrict__ Hprevb,
    const bf16u* __restrict__ xcb, const bf16u* __restrict__ ybb,
    const float* __restrict__ rbuf, const float* __restrict__ Dvec,
    bf16u* __restrict__ yout) {
  __shared__ bf16u sC[64 * LDP], sH[64 * LDP];
  __shared__ float sR[64];
  const int blk = blockIdx.x;
  const int bh = blk >> 4, c = blk & (NCHUNK - 1);
  const int b = bh >> 5, h = bh & (NHEADS - 1);
  const int t = threadIdx.x, lane = t & 63, wave = t >> 6;
  const int t0 = b * SEQLEN + c * 64;
  const size_t rowbase = (size_t)t0 * DINNER + h * 64;
  const size_t rowBC = (size_t)t0 * 4096 + h * 64;

#pragma unroll
  for (int it = 0; it < 2; ++it) {
    const int slot = it * 256 + t;          // 0..511
    const int r = slot >> 3, c8 = (slot & 7) * 8;
    *(short8*)&sC[r * LDP + c8] =
        *(const short8*)&BCb[rowBC + 2048 + (size_t)r * 4096 + c8];
    *(short8*)&sH[r * LDP + c8] =
        *(const short8*)&Hprevb[(size_t)blk * 4096 + slot * 8];
  }
  if (t < 64) sR[t] = rbuf[(size_t)blk * 64 + t];
  __syncthreads();

  const int ln15 = lane & 15, kq = lane >> 4;
  const int i0 = wave * 16;
  const f32x4 zero = {0.f, 0.f, 0.f, 0.f};
  f32x4 acc[4];
#pragma unroll
  for (int f = 0; f < 4; ++f) acc[f] = zero;
#pragma unroll
  for (int k0 = 0; k0 < 64; k0 += 32) {
    const short8 a = *(const short8*)&sC[(i0 + ln15) * LDP + k0 + kq * 8];
#pragma unroll
    for (int f = 0; f < 4; ++f) {
      const short8 bh8 = *(const short8*)&sH[(f * 16 + ln15) * LDP + k0 + kq * 8];
      acc[f] = __builtin_amdgcn_mfma_f32_16x16x32_bf16(a, bh8, acc[f], 0, 0, 0);
    }
  }
  const float Dh = Dvec[h];
  const bf16u* yb = ybb + (size_t)blk * 4096;
#pragma unroll
  for (int f = 0; f < 4; ++f) {
    const int p = f * 16 + ln15;
#pragma unroll
    for (int r = 0; r < 4; ++r) {
      const int i = i0 + kq * 4 + r;
      const float xv = b2f((short)xcb[rowbase + (size_t)i * DINNER + p]);
      const float y = b2f((short)yb[i * 64 + p]) + sR[i] * acc[f][r] + Dh * xv;
      yout[rowbase + (size_t)i * DINNER + p] = f2b(y);
    }
  }
}

// ---------------------------------------------------------------------------
// LayerNorm(2048) + SiLU(z) gate. bf16 y/z in, bf16 out. One block per token.
// ---------------------------------------------------------------------------
__global__ __launch_bounds__(256) void ln_gate(
    const bf16u* __restrict__ y, const bf16u* __restrict__ xzb,
    const float* __restrict__ lnw, const float* __restrict__ lnb,
    bf16u* __restrict__ out) {
  const int tok = blockIdx.x;
  const int t = threadIdx.x;
  const short8 yv8 = *(const short8*)(y + (size_t)tok * DINNER + t * 8);
  const short8 zv8 = *(const short8*)(xzb + (size_t)tok * (2 * DINNER) + DINNER + t * 8);
  float v[8];
  float s = 0.f, s2 = 0.f;
#pragma unroll
  for (int j = 0; j < 8; ++j) {
    v[j] = b2f(yv8[j]);
    s += v[j];
    s2 += v[j] * v[j];
  }
#pragma unroll
  for (int off = 32; off > 0; off >>= 1) {
    s += __shfl_down(s, off);
    s2 += __shfl_down(s2, off);
  }
  __shared__ float ws[4], ws2[4];
  const int wid = t >> 6;
  if ((t & 63) == 0) { ws[wid] = s; ws2[wid] = s2; }
  __syncthreads();
  const float mean = (ws[0] + ws[1] + ws[2] + ws[3]) * (1.f / DINNER);
  const float m2 = (ws2[0] + ws2[1] + ws2[2] + ws2[3]) * (1.f / DINNER);
  const float rstd = rsqrtf(m2 - mean * mean + 1e-5f);
  const float4 w0 = *(const float4*)(lnw + t * 8);
  const float4 w1 = *(const float4*)(lnw + t * 8 + 4);
  const float4 b0 = *(const float4*)(lnb + t * 8);
  const float4 b1 = *(const float4*)(lnb + t * 8 + 4);
  const float wv[8] = {w0.x, w0.y, w0.z, w0.w, w1.x, w1.y, w1.z, w1.w};
  const float bv[8] = {b0.x, b0.y, b0.z, b0.w, b1.x, b1.y, b1.z, b1.w};
  short8 o;
#pragma unroll
  for (int j = 0; j < 8; ++j) {
    const float zn = b2f(zv8[j]);
    const float gate = zn / (1.f + __expf(-zn));
    o[j] = (short)f2b(((v[j] - mean) * rstd * wv[j] + bv[j]) * gate);
  }
  *(short8*)(out + (size_t)tok * DINNER + t * 8) = o;
}

// ---------------------------------------------------------------------------
extern "C" void kernel_launch(void* const* d_in, const int* in_sizes, int n_in,
                              void* d_out, int out_size, void* d_ws, size_t ws_size,
                              hipStream_t stream) {
  const float* hidden = (const float*)d_in[0];
  const float* in_proj_w = (const float*)d_in[1];
  const float* conv_w = (const float*)d_in[2];
  const float* conv_b = (const float*)d_in[3];
  const float* A_log = (const float*)d_in[4];
  const float* dt_w = (const float*)d_in[5];
  const float* dt_b = (const float*)d_in[6];
  const float* B_w = (const float*)d_in[7];
  const float* C_w = (const float*)d_in[8];
  const float* Dv = (const float*)d_in[9];
  const float* ln_w = (const float*)d_in[10];
  const float* ln_b = (const float*)d_in[11];
  const float* out_proj_w = (const float*)d_in[12];

  float* out = (float*)d_out;
  float* f = (float*)d_ws;
  const size_t M1 = 1u << 20;

  // workspace layout (float-offset units) — r12 layout (known good):
  bf16u* xzb    = (bf16u*)(f + 0);            // [0,4M)   xz bf16 (8M elems)
  bf16u* xcb    = (bf16u*)(f + 4 * M1);       // [4M,6M)  conv out bf16
  bf16u* BCb    = (bf16u*)(f + 6 * M1);       // [6M,10M) fused B/C proj out
  bf16u* wBCb   = (bf16u*)(f + 10 * M1);      // [10M,14M) fused B/C weights (dead after BC gemm)
  bf16u* ybb    = (bf16u*)(f + 10 * M1);      // [10M,12M) y_intra bf16 (after wBCb dead)
  float* outp   = f + 6 * M1;                 // [6M,10M) 2 split-K partials (after BCb dead)
  bf16u* wInb   = (bf16u*)(f + 14 * M1);      // [14M,16M) (dead after in_proj)
  bf16u* hiddenb= (bf16u*)(f + 16 * M1);      // [16M,17M) (dead after in_proj)
  bf16u* wdtb   = (bf16u*)(f + 17 * M1);      // [17M,+32K) (dead after dt gemm)
  float* Sbuf   = f + 14 * M1;                // [14M,18M) (after wInb/hiddenb/wdtb dead)
  bf16u* ygb    = (bf16u*)(f + 14 * M1);      // [14M,16M) (after Sbuf dead)
  bf16u* yscb   = (bf16u*)(f + 16 * M1);      // [16M,18M) (after Sbuf dead)
  bf16u* Hprevb = (bf16u*)(f + 18 * M1);      // [18M,20M)
  bf16u* wOb    = (bf16u*)(f + 20 * M1);      // [20M,21M)
  float* dtbuf  = f + 21 * M1;                // [21M,+512K) 8 split-K partials
  float* rbuf   = f + 21 * M1 + 524288;       // [+64K]
  float* lambuf = f + 21 * M1 + 589824;       // [+1K]

  float* hf = out + OUT_ELEMS;

  // 0. all f32->bf16 conversions in ONE launch
  cvt_all<<<8224, 256, 0, stream>>>(hidden, hiddenb, in_proj_w, wInb,
                                    B_w, wBCb, C_w, wBCb + 4 * M1,
                                    out_proj_w, wOb, dt_w, wdtb);

  // 1. xz = hidden @ in_proj_w^T  [2048 x 4096], K=1024  (bf16 out)
  gemm_mfma<bf16u><<<dim3(64, 16, 1), 256, 0, stream>>>(
      hiddenb, wInb, xzb, NTOK, 2 * DINNER, DMODEL, DMODEL, DMODEL, 0);
  // 2. conv + SiLU -> xcb (bf16)
  conv_silu<<<2048, 256, 0, stream>>>(xzb, conv_w, conv_b, xcb);
  // 3. dt_raw = xc @ dt_w^T  [2048 x 32], K=2048, split-K=8 (f32 partials;
  //    softplus+sum fused into chunk_intra)
  gemm_mfma<float><<<dim3(1, 16, 8), 256, 0, stream>>>(
      xcb, wdtb, dtbuf, NTOK, NHEADS, DINNER / 8, DINNER, DINNER,
      (size_t)NTOK * NHEADS);
  // 4. fused B/C projection: [2048 x 4096], K=2048 (bf16 out)
  gemm_mfma<bf16u><<<dim3(64, 16, 1), 256, 0, stream>>>(
      xcb, wBCb, BCb, NTOK, 2 * DINNER, DINNER, DINNER, DINNER, 0);
  // 5. per-chunk intra + states (dt softplus fused in)
  chunk_intra<<<BATCH * NHEADS * NCHUNK, 256, 0, stream>>>(
      xcb, BCb, dtbuf, dt_b, A_log, ybb, Sbuf, rbuf, lambuf);
  // 6. inter-chunk scan (also writes h_final)
  chunk_scan<<<BATCH * NHEADS, 256, 0, stream>>>(Sbuf, lambuf, Hprevb, hf);
  // 7. combine -> y (bf16)
  chunk_inter<<<BATCH * NHEADS * NCHUNK, 256, 0, stream>>>(
      BCb, Hprevb, xcb, ybb, rbuf, Dv, yscb);
  // 8. LN + gate -> ygb (bf16)
  ln_gate<<<NTOK, 256, 0, stream>>>(yscb, xzb, ln_w, ln_b, ygb);
  // 9. out = yg @ out_proj_w^T  [2048 x 1024], K=2048, split-K=2 (f32 partials)
  gemm_mfma<float><<<dim3(16, 16, 2), 256, 0, stream>>>(
      ygb, wOb, outp, NTOK, DMODEL, DINNER / 2, DINNER, DINNER,
      (size_t)2 * M1);
  add_f32<<<2048, 256, 0, stream>>>(outp, outp + 2 * M1, out, OUT_ELEMS);
}

// Round 16
// 185.105 us; speedup vs baseline: 1.1498x; 1.0021x over previous
//
#include <hip/hip_runtime.h>
#include <math.h>

#define BATCH 2
#define SEQLEN 1024
#define DMODEL 1024
#define DINNER 2048
#define NHEADS 32
#define HEADDIM 64
#define DSTATE 64
#define NTOK (BATCH * SEQLEN)                 // 2048
#define OUT_ELEMS (BATCH * SEQLEN * DMODEL)   // 2097152
#define NCHUNK 16                             // chunks per sequence (Q=64)
#define LDP 72                                // padded LDS stride (bf16 elems)

typedef unsigned short bf16u;
typedef __attribute__((ext_vector_type(8))) short short8;
typedef __attribute__((ext_vector_type(4))) float f32x4;

__device__ __forceinline__ float b2f(short u) {
  return __uint_as_float(((unsigned)(unsigned short)u) << 16);
}
__device__ __forceinline__ unsigned short f2b(float f) {
  unsigned u = __float_as_uint(f);
  u += 0x7fff + ((u >> 16) & 1);   // RNE
  return (unsigned short)(u >> 16);
}

__device__ __forceinline__ void gload16(const void* g, void* l) {
  __builtin_amdgcn_global_load_lds(
      (const __attribute__((address_space(1))) unsigned int*)g,
      (__attribute__((address_space(3))) unsigned int*)l, 16, 0, 0);
}

__device__ __forceinline__ void stv(float* p, float v) { *p = v; }
__device__ __forceinline__ void stv(bf16u* p, float v) { *p = f2b(v); }

// ---------------------------------------------------------------------------
// Fused f32 -> bf16 conversion of all weights + hidden, one launch.
// ---------------------------------------------------------------------------
__global__ __launch_bounds__(256) void cvt_all(
    const float* __restrict__ s0, bf16u* __restrict__ d0,
    const float* __restrict__ s1, bf16u* __restrict__ d1,
    const float* __restrict__ s2, bf16u* __restrict__ d2,
    const float* __restrict__ s3, bf16u* __restrict__ d3,
    const float* __restrict__ s4, bf16u* __restrict__ d4,
    const float* __restrict__ s5, bf16u* __restrict__ d5) {
  const size_t M1 = 1u << 20;
  size_t i = (size_t)(blockIdx.x * 256 + threadIdx.x) * 8;
  const float* src; bf16u* dst; size_t off;
  if (i < 2 * M1)       { src = s0; dst = d0; off = i; }
  else if (i < 6 * M1)  { src = s1; dst = d1; off = i - 2 * M1; }
  else if (i < 10 * M1) { src = s2; dst = d2; off = i - 6 * M1; }
  else if (i < 14 * M1) { src = s3; dst = d3; off = i - 10 * M1; }
  else if (i < 16 * M1) { src = s4; dst = d4; off = i - 14 * M1; }
  else if (i < 16 * M1 + 65536) { src = s5; dst = d5; off = i - 16 * M1; }
  else return;
  const float4 a = *(const float4*)(src + off);
  const float4 b = *(const float4*)(src + off + 4);
  short8 o;
  o[0] = f2b(a.x); o[1] = f2b(a.y); o[2] = f2b(a.z); o[3] = f2b(a.w);
  o[4] = f2b(b.x); o[5] = f2b(b.y); o[6] = f2b(b.z); o[7] = f2b(b.w);
  *(short8*)(dst + off) = o;
}

// ---------------------------------------------------------------------------
// bf16 MFMA GEMM (r10-proven config):  C[m,n] = sum_k A[m][k+kbase]*B[n][k+kbase]
// Tile 128x64, BK=32, 256 threads (2x2 waves of 64x32), 36KB ring-3 LDS
// (4 blocks/CU). Single barrier/iter, reads-before-barrier, counted vmcnt
// distance-1. T1 XCD-chunked swizzle, M-fastest decode. grid.z = split-K
// slices; writes to C + z*zstrideC (plain stores only — deterministic).
// ---------------------------------------------------------------------------
template <typename OutT>
__global__ __launch_bounds__(256) void gemm_mfma(
    const bf16u* __restrict__ A, const bf16u* __restrict__ B,
    OutT* __restrict__ C, int M, int N, int Ksub, int lda, int ldb,
    size_t zstrideC) {
  __shared__ bf16u sA[3][128 * 32];   // 8KB / buffer
  __shared__ bf16u sB[3][64 * 32];    // 4KB / buffer
  const int t = threadIdx.x;
  const int lane = t & 63, wave = t >> 6;
  // T1 swizzle (requires nwg % 8 == 0)
  const int nwg = gridDim.x * gridDim.y;
  const int fid = blockIdx.y * gridDim.x + blockIdx.x;
  const int tile = (fid & 7) * (nwg >> 3) + (fid >> 3);
  const int bm = (tile % gridDim.y) * 128;
  const int bn = (tile / gridDim.y) * 64;
  const int wr = wave >> 1, wc = wave & 1;
  const int kbase = blockIdx.z * Ksub;
  OutT* Cz = C + (size_t)blockIdx.z * zstrideC;

  const int ra0 = bm + (t >> 2), ra1 = bm + 64 + (t >> 2);
  int rb0 = bn + (t >> 2);
  rb0 = rb0 < N ? rb0 : N - 1;
  const int kc = (((t & 3) ^ ((t >> 4) & 3))) * 8;

  const bf16u* Ap0 = A + (size_t)ra0 * lda + kbase + kc;
  const bf16u* Ap1 = A + (size_t)ra1 * lda + kbase + kc;
  const bf16u* Bp0 = B + (size_t)rb0 * ldb + kbase + kc;
  const int ldsoff = (wave * 64) * 8;

#define STAGE(buf, k0)                                   \
  do {                                                   \
    gload16(Ap0 + (k0), sA[buf] + ldsoff);               \
    gload16(Ap1 + (k0), sA[buf] + 2048 + ldsoff);        \
    gload16(Bp0 + (k0), sB[buf] + ldsoff);               \
  } while (0)

  const f32x4 zero = {0.f, 0.f, 0.f, 0.f};
  f32x4 acc[4][2];
#pragma unroll
  for (int m = 0; m < 4; ++m)
#pragma unroll
    for (int n = 0; n < 2; ++n) acc[m][n] = zero;

  const int ln15 = lane & 15, kq = lane >> 4;
  const int kswz = ((kq ^ ((ln15 >> 2) & 3))) * 8;
  const int nt = Ksub >> 5;

  STAGE(0, 0);
  STAGE(1, 32);
  int curb = 0;
  for (int it = 0; it < nt; ++it) {
    if (it + 2 < nt) {
      const int nb = (it + 2) % 3;
      STAGE(nb, (it + 2) * 32);
      asm volatile("s_waitcnt vmcnt(3)" ::: "memory");
    } else {
      asm volatile("s_waitcnt vmcnt(0)" ::: "memory");
    }
    const bf16u* pA = sA[curb];
    const bf16u* pB = sB[curb];
    short8 af[4], bfr[2];
#pragma unroll
    for (int m = 0; m < 4; ++m)
      af[m] = *(const short8*)&pA[(wr * 64 + m * 16 + ln15) * 32 + kswz];
#pragma unroll
    for (int n = 0; n < 2; ++n)
      bfr[n] = *(const short8*)&pB[(wc * 32 + n * 16 + ln15) * 32 + kswz];
    asm volatile("s_waitcnt lgkmcnt(0)" ::: "memory");
    __builtin_amdgcn_sched_barrier(0);
    __builtin_amdgcn_s_barrier();
    __builtin_amdgcn_s_setprio(1);
#pragma unroll
    for (int m = 0; m < 4; ++m)
#pragma unroll
      for (int n = 0; n < 2; ++n)
        acc[m][n] = __builtin_amdgcn_mfma_f32_16x16x32_bf16(af[m], bfr[n], acc[m][n], 0, 0, 0);
    __builtin_amdgcn_s_setprio(0);
    curb = (curb == 2) ? 0 : curb + 1;
  }
#undef STAGE

  const int rbase = bm + wr * 64, cbase = bn + wc * 32;
#pragma unroll
  for (int m = 0; m < 4; ++m) {
#pragma unroll
    for (int n = 0; n < 2; ++n) {
      const int col = cbase + n * 16 + ln15;
      if (col < N) {
#pragma unroll
        for (int r = 0; r < 4; ++r) {
          const int row = rbase + m * 16 + kq * 4 + r;
          stv(&Cz[(size_t)row * N + col], acc[m][n][r]);
        }
      }
    }
  }
}

// ---------------------------------------------------------------------------
// Combined BC + dt projection dispatch. 1152 blocks:
//   fid < 1024 : BC tile (M=2048,N=4096,K=2048), T1 swizzle over 1024,
//                bf16 out to BCb.
//   fid >= 1024: dt tile (M=2048,N=32, split-K=8, Ksub=256), f32 partials to
//                dtbuf + z*65536. Rides the BC dispatch's tail round instead
//                of a separate 128-WG latency-bound launch.
// Whole-block branch; disjoint outputs; same r10-proven inner loop.
// ---------------------------------------------------------------------------
__global__ __launch_bounds__(256) void gemm_bc_dt(
    const bf16u* __restrict__ A, const bf16u* __restrict__ Wbc,
    const bf16u* __restrict__ Wdt, bf16u* __restrict__ BCb,
    float* __restrict__ dtbuf) {
  __shared__ bf16u sA[3][128 * 32];
  __shared__ bf16u sB[3][64 * 32];
  const int t = threadIdx.x;
  const int lane = t & 63, wave = t >> 6;
  const int fid = blockIdx.x;

  int bm, bn, kbase, nt, N, zdt = 0;
  const bf16u* Bw;
  bool isdt;
  if (fid < 1024) {
    isdt = false;
    const int tile = (fid & 7) * 128 + (fid >> 3);   // T1 over exactly 1024
    bm = (tile % 16) * 128;
    bn = (tile / 16) * 64;
    kbase = 0; nt = 64; N = 4096; Bw = Wbc;
  } else {
    isdt = true;
    const int did = fid - 1024;       // 0..127
    zdt = did >> 4;                   // split-K slice 0..7
    bm = (did & 15) * 128;
    bn = 0;
    kbase = zdt * 256; nt = 8; N = 32; Bw = Wdt;
  }
  const int wr = wave >> 1, wc = wave & 1;

  const int ra0 = bm + (t >> 2), ra1 = bm + 64 + (t >> 2);
  int rb0 = bn + (t >> 2);
  rb0 = rb0 < N ? rb0 : N - 1;
  const int kc = (((t & 3) ^ ((t >> 4) & 3))) * 8;

  const bf16u* Ap0 = A + (size_t)ra0 * 2048 + kbase + kc;
  const bf16u* Ap1 = A + (size_t)ra1 * 2048 + kbase + kc;
  const bf16u* Bp0 = Bw + (size_t)rb0 * 2048 + kbase + kc;
  const int ldsoff = (wave * 64) * 8;

#define STAGE(buf, k0)                                   \
  do {                                                   \
    gload16(Ap0 + (k0), sA[buf] + ldsoff);               \
    gload16(Ap1 + (k0), sA[buf] + 2048 + ldsoff);        \
    gload16(Bp0 + (k0), sB[buf] + ldsoff);               \
  } while (0)

  const f32x4 zero = {0.f, 0.f, 0.f, 0.f};
  f32x4 acc[4][2];
#pragma unroll
  for (int m = 0; m < 4; ++m)
#pragma unroll
    for (int n = 0; n < 2; ++n) acc[m][n] = zero;

  const int ln15 = lane & 15, kq = lane >> 4;
  const int kswz = ((kq ^ ((ln15 >> 2) & 3))) * 8;

  STAGE(0, 0);
  STAGE(1, 32);
  int curb = 0;
  for (int it = 0; it < nt; ++it) {
    if (it + 2 < nt) {
      const int nb = (it + 2) % 3;
      STAGE(nb, (it + 2) * 32);
      asm volatile("s_waitcnt vmcnt(3)" ::: "memory");
    } else {
      asm volatile("s_waitcnt vmcnt(0)" ::: "memory");
    }
    const bf16u* pA = sA[curb];
    const bf16u* pB = sB[curb];
    short8 af[4], bfr[2];
#pragma unroll
    for (int m = 0; m < 4; ++m)
      af[m] = *(const short8*)&pA[(wr * 64 + m * 16 + ln15) * 32 + kswz];
#pragma unroll
    for (int n = 0; n < 2; ++n)
      bfr[n] = *(const short8*)&pB[(wc * 32 + n * 16 + ln15) * 32 + kswz];
    asm volatile("s_waitcnt lgkmcnt(0)" ::: "memory");
    __builtin_amdgcn_sched_barrier(0);
    __builtin_amdgcn_s_barrier();
    __builtin_amdgcn_s_setprio(1);
#pragma unroll
    for (int m = 0; m < 4; ++m)
#pragma unroll
      for (int n = 0; n < 2; ++n)
        acc[m][n] = __builtin_amdgcn_mfma_f32_16x16x32_bf16(af[m], bfr[n], acc[m][n], 0, 0, 0);
    __builtin_amdgcn_s_setprio(0);
    curb = (curb == 2) ? 0 : curb + 1;
  }
#undef STAGE

  const int rbase = bm + wr * 64, cbase = bn + wc * 32;
  if (!isdt) {
#pragma unroll
    for (int m = 0; m < 4; ++m) {
#pragma unroll
      for (int n = 0; n < 2; ++n) {
        const int col = cbase + n * 16 + ln15;
#pragma unroll
        for (int r = 0; r < 4; ++r) {
          const int row = rbase + m * 16 + kq * 4 + r;
          BCb[(size_t)row * 4096 + col] = f2b(acc[m][n][r]);
        }
      }
    }
  } else {
    float* Cz = dtbuf + (size_t)zdt * 65536;
#pragma unroll
    for (int m = 0; m < 4; ++m) {
#pragma unroll
      for (int n = 0; n < 2; ++n) {
        const int col = cbase + n * 16 + ln15;
        if (col < 32) {
#pragma unroll
          for (int r = 0; r < 4; ++r) {
            const int row = rbase + m * 16 + kq * 4 + r;
            Cz[(size_t)row * 32 + col] = acc[m][n][r];
          }
        }
      }
    }
  }
}

// ---------------------------------------------------------------------------
// out = a + b (f32), 4 elems/thread
// ---------------------------------------------------------------------------
__global__ __launch_bounds__(256) void add_f32(const float* __restrict__ a,
                                               const float* __restrict__ b,
                                               float* __restrict__ o, int n) {
  const int i = (blockIdx.x * 256 + threadIdx.x) * 4;
  if (i >= n) return;
  const float4 x = *(const float4*)(a + i);
  const float4 y = *(const float4*)(b + i);
  *(float4*)(o + i) = make_float4(x.x + y.x, x.y + y.y, x.z + y.z, x.w + y.w);
}

// ---------------------------------------------------------------------------
// Depthwise causal conv (width 4) + bias + SiLU. bf16 in/out.
// ---------------------------------------------------------------------------
__global__ __launch_bounds__(256) void conv_silu(
    const bf16u* __restrict__ xzb, const float* __restrict__ cw,
    const float* __restrict__ cb, bf16u* __restrict__ xcb) {
  const int i = blockIdx.x * 256 + threadIdx.x;  // 0..512K
  const int c8 = (i & 255) * 8;
  const int tok = i >> 8;
  const int l = tok & (SEQLEN - 1);
  const bf16u* xp = xzb + (size_t)tok * (2 * DINNER) + c8;
  const short8 zer = {0, 0, 0, 0, 0, 0, 0, 0};
  const short8 x0 = *(const short8*)xp;
  const short8 x1 = (l >= 1) ? *(const short8*)(xp - 1 * (2 * DINNER)) : zer;
  const short8 x2 = (l >= 2) ? *(const short8*)(xp - 2 * (2 * DINNER)) : zer;
  const short8 x3 = (l >= 3) ? *(const short8*)(xp - 3 * (2 * DINNER)) : zer;
  short8 ob;
#pragma unroll
  for (int j = 0; j < 8; ++j) {
    const float4 w = *(const float4*)(cw + (c8 + j) * 4);
    float acc = cb[c8 + j] + w.w * b2f(x0[j]);
    acc += w.z * b2f(x1[j]);
    acc += w.y * b2f(x2[j]);
    acc += w.x * b2f(x3[j]);
    const float s = acc / (1.f + __expf(-acc));
    ob[j] = (short)f2b(s);
  }
  *(short8*)(xcb + (size_t)tok * DINNER + c8) = ob;
}

// ---------------------------------------------------------------------------
// Chunked SSD, stage 1 (per chunk): dt softplus (fused from 8 split-K
// partials), decay cumsum, G=C@B^T masked -> P, Y_intra = P@X (bf16 out),
// S = X^T diag(w) B. One block per (b,h,c).
// BCb [NTOK,4096]: cols [0,2048)=B, [2048,4096)=C.
// ---------------------------------------------------------------------------
__global__ __launch_bounds__(256) void chunk_intra(
    const bf16u* __restrict__ xcb, const bf16u* __restrict__ BCb,
    const float* __restrict__ dtp8, const float* __restrict__ dt_b,
    const float* __restrict__ A_log,
    bf16u* __restrict__ ybb, float* __restrict__ Sbuf,
    float* __restrict__ rbuf, float* __restrict__ lambuf) {
  __shared__ bf16u sC[64 * LDP], sB[64 * LDP], sXT[64 * LDP];
  __shared__ bf16u sWBT[64 * LDP], sP[64 * LDP];
  __shared__ float sS[64], sDt[64], sW[64];

  const int blk = blockIdx.x;
  const int bh = blk >> 4, c = blk & (NCHUNK - 1);
  const int b = bh >> 5, h = bh & (NHEADS - 1);
  const int t = threadIdx.x, lane = t & 63, wave = t >> 6;
  const int t0 = b * SEQLEN + c * 64;
  const size_t rowbase = (size_t)t0 * DINNER + h * 64;        // x
  const size_t rowBC = (size_t)t0 * 4096 + h * 64;            // fused B/C

  // ---- P0: staging + dt softplus + decay scan ----
  if (wave == 0) {
    const size_t di = (size_t)(t0 + lane) * NHEADS + h;
    float dr = dt_b[h];
#pragma unroll
    for (int k = 0; k < 8; ++k) dr += dtp8[di + (size_t)k * 65536];
    const float dtv = (dr > 20.f) ? dr : log1pf(__expf(dr));
    const float Ah = -__expf(A_log[h]);
    float s = Ah * dtv;
#pragma unroll
    for (int off = 1; off < 64; off <<= 1) {
      const float o = __shfl_up(s, off);
      if (lane >= off) s += o;
    }
    const float stot = __shfl(s, 63);
    sS[lane] = s;
    sDt[lane] = dtv;
    sW[lane] = __expf(stot - s) * dtv;
    rbuf[(size_t)blk * 64 + lane] = __expf(s);
    if (lane == 0) lambuf[blk] = __expf(stot);
  } else if (wave == 1) {
#pragma unroll
    for (int it = 0; it < 8; ++it) {
      const int slot = it * 64 + lane;
      const int r = slot >> 3, c8 = (slot & 7) * 8;
      *(short8*)&sC[r * LDP + c8] =
          *(const short8*)&BCb[rowBC + 2048 + (size_t)r * 4096 + c8];
    }
  } else if (wave == 2) {
#pragma unroll
    for (int it = 0; it < 8; ++it) {
      const int slot = it * 64 + lane;
      const int r = slot >> 3, c8 = (slot & 7) * 8;
      *(short8*)&sB[r * LDP + c8] =
          *(const short8*)&BCb[rowBC + (size_t)r * 4096 + c8];
    }
  } else {
#pragma unroll
    for (int it = 0; it < 8; ++it) {
      const int slot = it * 64 + lane;
      const int j = slot >> 3, p0 = (slot & 7) * 8;
      const short8 v = *(const short8*)&xcb[rowbase + (size_t)j * DINNER + p0];
#pragma unroll
      for (int k = 0; k < 8; ++k) sXT[(p0 + k) * LDP + j] = v[k];
    }
  }
  __syncthreads();

  // ---- P1: WBT[n][j] = w_j * B[j][n]; G mfma + mask -> P ----
  {
    const int j = t >> 2, n0 = (t & 3) * 16;
    const float wj = sW[j];
#pragma unroll
    for (int k = 0; k < 16; ++k)
      sWBT[(n0 + k) * LDP + j] = f2b(wj * b2f(sB[j * LDP + n0 + k]));
  }
  const int ln15 = lane & 15, kq = lane >> 4;
  const int i0 = wave * 16;
  const f32x4 zero = {0.f, 0.f, 0.f, 0.f};
  {
    f32x4 g[4];
#pragma unroll
    for (int jf = 0; jf < 4; ++jf) g[jf] = zero;
#pragma unroll
    for (int k0 = 0; k0 < 64; k0 += 32) {
      const short8 a = *(const short8*)&sC[(i0 + ln15) * LDP + k0 + kq * 8];
#pragma unroll
      for (int jf = 0; jf < 4; ++jf) {
        const short8 bb = *(const short8*)&sB[(jf * 16 + ln15) * LDP + k0 + kq * 8];
        g[jf] = __builtin_amdgcn_mfma_f32_16x16x32_bf16(a, bb, g[jf], 0, 0, 0);
      }
    }
#pragma unroll
    for (int jf = 0; jf < 4; ++jf) {
      const int j = jf * 16 + ln15;
      const float sj = sS[j], dtj = sDt[j];
#pragma unroll
      for (int r = 0; r < 4; ++r) {
        const int i = i0 + kq * 4 + r;
        const float v = (j <= i) ? g[jf][r] * __expf(sS[i] - sj) * dtj : 0.f;
        sP[i * LDP + j] = f2b(v);
      }
    }
  }
  __syncthreads();

  // ---- P2: Y_intra = P @ XT^T ; S = XT @ WBT^T ----
  f32x4 yi[4], ss[4];
#pragma unroll
  for (int f = 0; f < 4; ++f) { yi[f] = zero; ss[f] = zero; }
#pragma unroll
  for (int k0 = 0; k0 < 64; k0 += 32) {
    const short8 ap = *(const short8*)&sP[(i0 + ln15) * LDP + k0 + kq * 8];
    const short8 ax = *(const short8*)&sXT[(i0 + ln15) * LDP + k0 + kq * 8];
#pragma unroll
    for (int f = 0; f < 4; ++f) {
      const short8 bx = *(const short8*)&sXT[(f * 16 + ln15) * LDP + k0 + kq * 8];
      const short8 bw = *(const short8*)&sWBT[(f * 16 + ln15) * LDP + k0 + kq * 8];
      yi[f] = __builtin_amdgcn_mfma_f32_16x16x32_bf16(ap, bx, yi[f], 0, 0, 0);
      ss[f] = __builtin_amdgcn_mfma_f32_16x16x32_bf16(ax, bw, ss[f], 0, 0, 0);
    }
  }
  bf16u* yb = ybb + (size_t)blk * 4096;
  float* sb = Sbuf + (size_t)blk * 4096;
#pragma unroll
  for (int f = 0; f < 4; ++f) {
#pragma unroll
    for (int r = 0; r < 4; ++r) {
      const int row = i0 + kq * 4 + r;
      const int col = f * 16 + ln15;
      yb[row * 64 + col] = f2b(yi[f][r]);
      sb[row * 64 + col] = ss[f][r];
    }
  }
}

// ---------------------------------------------------------------------------
// Chunked SSD, stage 2: inter-chunk state scan (16 steps, scalar decay).
// ---------------------------------------------------------------------------
__global__ __launch_bounds__(256) void chunk_scan(
    const float* __restrict__ Sbuf, const float* __restrict__ lambuf,
    bf16u* __restrict__ Hprevb, float* __restrict__ hf) {
  const int bh = blockIdx.x;
  const int t = threadIdx.x;
  const int e0 = t * 16;
  float H[16];
#pragma unroll
  for (int j = 0; j < 16; ++j) H[j] = 0.f;

  float4 cur[4];
  float lam;
  {
    const float4* sp = (const float4*)(Sbuf + (size_t)(bh * NCHUNK) * 4096 + e0);
#pragma unroll
    for (int q = 0; q < 4; ++q) cur[q] = sp[q];
    lam = lambuf[bh * NCHUNK];
  }
  for (int c = 0; c < NCHUNK; ++c) {
    float4 nxt[4];
    float lamn = 0.f;
    if (c < NCHUNK - 1) {
      const float4* sp = (const float4*)(Sbuf + (size_t)(bh * NCHUNK + c + 1) * 4096 + e0);
#pragma unroll
      for (int q = 0; q < 4; ++q) nxt[q] = sp[q];
      lamn = lambuf[bh * NCHUNK + c + 1];
    }
    short8 o0, o1;
#pragma unroll
    for (int j = 0; j < 8; ++j) o0[j] = (short)f2b(H[j]);
#pragma unroll
    for (int j = 0; j < 8; ++j) o1[j] = (short)f2b(H[8 + j]);
    *(short8*)&Hprevb[(size_t)(bh * NCHUNK + c) * 4096 + e0] = o0;
    *(short8*)&Hprevb[(size_t)(bh * NCHUNK + c) * 4096 + e0 + 8] = o1;
#pragma unroll
    for (int q = 0; q < 4; ++q) {
      H[q * 4 + 0] = lam * H[q * 4 + 0] + cur[q].x;
      H[q * 4 + 1] = lam * H[q * 4 + 1] + cur[q].y;
      H[q * 4 + 2] = lam * H[q * 4 + 2] + cur[q].z;
      H[q * 4 + 3] = lam * H[q * 4 + 3] + cur[q].w;
    }
#pragma unroll
    for (int q = 0; q < 4; ++q) cur[q] = nxt[q];
    lam = lamn;
  }
  float* hp = hf + (size_t)bh * 4096 + e0;
#pragma unroll
  for (int q = 0; q < 4; ++q)
    *(float4*)(hp + q * 4) =
        make_float4(H[q * 4], H[q * 4 + 1], H[q * 4 + 2], H[q * 4 + 3]);
}

// ---------------------------------------------------------------------------
// Chunked SSD, stage 3 (per chunk): Y = Y_intra + r_i * C @ Hprev^T + D*x.
// ---------------------------------------------------------------------------
__global__ __launch_bounds__(256) void chunk_inter(
    const bf16u* __restrict__ BCb, const bf16u* __restrict__ Hprevb,
    const bf16u* __restrict__ xcb, const bf16u* __restrict__ ybb,
    const float* __restrict__ rbuf, const float* __restrict__ Dvec,
    bf16u* __restrict__ yout) {
  __shared__ bf16u sC[64 * LDP], sH[64 * LDP];
  __shared__ float sR[64];
  const int blk = blockIdx.x;
  const int bh = blk >> 4, c = blk & (NCHUNK - 1);
  const int b = bh >> 5, h = bh & (NHEADS - 1);
  const int t = threadIdx.x, lane = t & 63, wave = t >> 6;
  const int t0 = b * SEQLEN + c * 64;
  const size_t rowbase = (size_t)t0 * DINNER + h * 64;
  const size_t rowBC = (size_t)t0 * 4096 + h * 64;

#pragma unroll
  for (int it = 0; it < 2; ++it) {
    const int slot = it * 256 + t;          // 0..511
    const int r = slot >> 3, c8 = (slot & 7) * 8;
    *(short8*)&sC[r * LDP + c8] =
        *(const short8*)&BCb[rowBC + 2048 + (size_t)r * 4096 + c8];
    *(short8*)&sH[r * LDP + c8] =
        *(const short8*)&Hprevb[(size_t)blk * 4096 + slot * 8];
  }
  if (t < 64) sR[t] = rbuf[(size_t)blk * 64 + t];
  __syncthreads();

  const int ln15 = lane & 15, kq = lane >> 4;
  const int i0 = wave * 16;
  const f32x4 zero = {0.f, 0.f, 0.f, 0.f};
  f32x4 acc[4];
#pragma unroll
  for (int f = 0; f < 4; ++f) acc[f] = zero;
#pragma unroll
  for (int k0 = 0; k0 < 64; k0 += 32) {
    const short8 a = *(const short8*)&sC[(i0 + ln15) * LDP + k0 + kq * 8];
#pragma unroll
    for (int f = 0; f < 4; ++f) {
      const short8 bh8 = *(const short8*)&sH[(f * 16 + ln15) * LDP + k0 + kq * 8];
      acc[f] = __builtin_amdgcn_mfma_f32_16x16x32_bf16(a, bh8, acc[f], 0, 0, 0);
    }
  }
  const float Dh = Dvec[h];
  const bf16u* yb = ybb + (size_t)blk * 4096;
#pragma unroll
  for (int f = 0; f < 4; ++f) {
    const int p = f * 16 + ln15;
#pragma unroll
    for (int r = 0; r < 4; ++r) {
      const int i = i0 + kq * 4 + r;
      const float xv = b2f((short)xcb[rowbase + (size_t)i * DINNER + p]);
      const float y = b2f((short)yb[i * 64 + p]) + sR[i] * acc[f][r] + Dh * xv;
      yout[rowbase + (size_t)i * DINNER + p] = f2b(y);
    }
  }
}

// ---------------------------------------------------------------------------
// LayerNorm(2048) + SiLU(z) gate. bf16 y/z in, bf16 out. One block per token.
// ---------------------------------------------------------------------------
__global__ __launch_bounds__(256) void ln_gate(
    const bf16u* __restrict__ y, const bf16u* __restrict__ xzb,
    const float* __restrict__ lnw, const float* __restrict__ lnb,
    bf16u* __restrict__ out) {
  const int tok = blockIdx.x;
  const int t = threadIdx.x;
  const short8 yv8 = *(const short8*)(y + (size_t)tok * DINNER + t * 8);
  const short8 zv8 = *(const short8*)(xzb + (size_t)tok * (2 * DINNER) + DINNER + t * 8);
  float v[8];
  float s = 0.f, s2 = 0.f;
#pragma unroll
  for (int j = 0; j < 8; ++j) {
    v[j] = b2f(yv8[j]);
    s += v[j];
    s2 += v[j] * v[j];
  }
#pragma unroll
  for (int off = 32; off > 0; off >>= 1) {
    s += __shfl_down(s, off);
    s2 += __shfl_down(s2, off);
  }
  __shared__ float ws[4], ws2[4];
  const int wid = t >> 6;
  if ((t & 63) == 0) { ws[wid] = s; ws2[wid] = s2; }
  __syncthreads();
  const float mean = (ws[0] + ws[1] + ws[2] + ws[3]) * (1.f / DINNER);
  const float m2 = (ws2[0] + ws2[1] + ws2[2] + ws2[3]) * (1.f / DINNER);
  const float rstd = rsqrtf(m2 - mean * mean + 1e-5f);
  const float4 w0 = *(const float4*)(lnw + t * 8);
  const float4 w1 = *(const float4*)(lnw + t * 8 + 4);
  const float4 b0 = *(const float4*)(lnb + t * 8);
  const float4 b1 = *(const float4*)(lnb + t * 8 + 4);
  const float wv[8] = {w0.x, w0.y, w0.z, w0.w, w1.x, w1.y, w1.z, w1.w};
  const float bv[8] = {b0.x, b0.y, b0.z, b0.w, b1.x, b1.y, b1.z, b1.w};
  short8 o;
#pragma unroll
  for (int j = 0; j < 8; ++j) {
    const float zn = b2f(zv8[j]);
    const float gate = zn / (1.f + __expf(-zn));
    o[j] = (short)f2b(((v[j] - mean) * rstd * wv[j] + bv[j]) * gate);
  }
  *(short8*)(out + (size_t)tok * DINNER + t * 8) = o;
}

// ---------------------------------------------------------------------------
extern "C" void kernel_launch(void* const* d_in, const int* in_sizes, int n_in,
                              void* d_out, int out_size, void* d_ws, size_t ws_size,
                              hipStream_t stream) {
  const float* hidden = (const float*)d_in[0];
  const float* in_proj_w = (const float*)d_in[1];
  const float* conv_w = (const float*)d_in[2];
  const float* conv_b = (const float*)d_in[3];
  const float* A_log = (const float*)d_in[4];
  const float* dt_w = (const float*)d_in[5];
  const float* dt_b = (const float*)d_in[6];
  const float* B_w = (const float*)d_in[7];
  const float* C_w = (const float*)d_in[8];
  const float* Dv = (const float*)d_in[9];
  const float* ln_w = (const float*)d_in[10];
  const float* ln_b = (const float*)d_in[11];
  const float* out_proj_w = (const float*)d_in[12];

  float* out = (float*)d_out;
  float* f = (float*)d_ws;
  const size_t M1 = 1u << 20;

  // workspace layout (float-offset units) — r12/r15 layout (known good):
  bf16u* xzb    = (bf16u*)(f + 0);            // [0,4M)   xz bf16 (8M elems)
  bf16u* xcb    = (bf16u*)(f + 4 * M1);       // [4M,6M)  conv out bf16
  bf16u* BCb    = (bf16u*)(f + 6 * M1);       // [6M,10M) fused B/C proj out
  bf16u* wBCb   = (bf16u*)(f + 10 * M1);      // [10M,14M) fused B/C weights (dead after BC gemm)
  bf16u* ybb    = (bf16u*)(f + 10 * M1);      // [10M,12M) y_intra bf16 (after wBCb dead)
  float* outp   = f + 6 * M1;                 // [6M,10M) 2 split-K partials (after BCb dead)
  bf16u* wInb   = (bf16u*)(f + 14 * M1);      // [14M,16M) (dead after in_proj)
  bf16u* hiddenb= (bf16u*)(f + 16 * M1);      // [16M,17M) (dead after in_proj)
  bf16u* wdtb   = (bf16u*)(f + 17 * M1);      // [17M,+32K) (dead after bc_dt gemm)
  float* Sbuf   = f + 14 * M1;                // [14M,18M) (after wInb/hiddenb/wdtb dead)
  bf16u* ygb    = (bf16u*)(f + 14 * M1);      // [14M,16M) (after Sbuf dead)
  bf16u* yscb   = (bf16u*)(f + 16 * M1);      // [16M,18M) (after Sbuf dead)
  bf16u* Hprevb = (bf16u*)(f + 18 * M1);      // [18M,20M)
  bf16u* wOb    = (bf16u*)(f + 20 * M1);      // [20M,21M)
  float* dtbuf  = f + 21 * M1;                // [21M,+512K) 8 split-K partials
  float* rbuf   = f + 21 * M1 + 524288;       // [+64K]
  float* lambuf = f + 21 * M1 + 589824;       // [+1K]

  float* hf = out + OUT_ELEMS;

  // 0. all f32->bf16 conversions in ONE launch
  cvt_all<<<8224, 256, 0, stream>>>(hidden, hiddenb, in_proj_w, wInb,
                                    B_w, wBCb, C_w, wBCb + 4 * M1,
                                    out_proj_w, wOb, dt_w, wdtb);

  // 1. xz = hidden @ in_proj_w^T  [2048 x 4096], K=1024  (bf16 out)
  gemm_mfma<bf16u><<<dim3(64, 16, 1), 256, 0, stream>>>(
      hiddenb, wInb, xzb, NTOK, 2 * DINNER, DMODEL, DMODEL, DMODEL, 0);
  // 2. conv + SiLU -> xcb (bf16)
  conv_silu<<<2048, 256, 0, stream>>>(xzb, conv_w, conv_b, xcb);
  // 3. combined: fused B/C projection (1024 tiles) + dt split-K=8 (128 tiles)
  gemm_bc_dt<<<1152, 256, 0, stream>>>(xcb, wBCb, wdtb, BCb, dtbuf);
  // 4. per-chunk intra + states (dt softplus fused in)
  chunk_intra<<<BATCH * NHEADS * NCHUNK, 256, 0, stream>>>(
      xcb, BCb, dtbuf, dt_b, A_log, ybb, Sbuf, rbuf, lambuf);
  // 5. inter-chunk scan (also writes h_final)
  chunk_scan<<<BATCH * NHEADS, 256, 0, stream>>>(Sbuf, lambuf, Hprevb, hf);
  // 6. combine -> y (bf16)
  chunk_inter<<<BATCH * NHEADS * NCHUNK, 256, 0, stream>>>(
      BCb, Hprevb, xcb, ybb, rbuf, Dv, yscb);
  // 7. LN + gate -> ygb (bf16)
  ln_gate<<<NTOK, 256, 0, stream>>>(yscb, xzb, ln_w, ln_b, ygb);
  // 8. out = yg @ out_proj_w^T  [2048 x 1024], K=2048, split-K=2 (f32 partials)
  gemm_mfma<float><<<dim3(16, 16, 2), 256, 0, stream>>>(
      ygb, wOb, outp, NTOK, DMODEL, DINNER / 2, DINNER, DINNER,
      (size_t)2 * M1);
  add_f32<<<2048, 256, 0, stream>>>(outp, outp + 2 * M1, out, OUT_ELEMS);
}

// Round 17
// 183.957 us; speedup vs baseline: 1.1570x; 1.0062x over previous
//
#include <hip/hip_runtime.h>
#include <math.h>

#define BATCH 2
#define SEQLEN 1024
#define DMODEL 1024
#define DINNER 2048
#define NHEADS 32
#define HEADDIM 64
#define DSTATE 64
#define NTOK (BATCH * SEQLEN)                 // 2048
#define OUT_ELEMS (BATCH * SEQLEN * DMODEL)   // 2097152
#define NCHUNK 16                             // chunks per sequence (Q=64)
#define LDP 72                                // padded LDS stride (bf16 elems)

typedef unsigned short bf16u;
typedef __attribute__((ext_vector_type(8))) short short8;
typedef __attribute__((ext_vector_type(4))) float f32x4;

__device__ __forceinline__ float b2f(short u) {
  return __uint_as_float(((unsigned)(unsigned short)u) << 16);
}
__device__ __forceinline__ unsigned short f2b(float f) {
  unsigned u = __float_as_uint(f);
  u += 0x7fff + ((u >> 16) & 1);   // RNE
  return (unsigned short)(u >> 16);
}

__device__ __forceinline__ void gload16(const void* g, void* l) {
  __builtin_amdgcn_global_load_lds(
      (const __attribute__((address_space(1))) unsigned int*)g,
      (__attribute__((address_space(3))) unsigned int*)l, 16, 0, 0);
}

__device__ __forceinline__ void stv(float* p, float v) { *p = v; }
__device__ __forceinline__ void stv(bf16u* p, float v) { *p = f2b(v); }

__device__ __forceinline__ void cvt8(const float* __restrict__ src,
                                     bf16u* __restrict__ dst, size_t off) {
  const float4 a = *(const float4*)(src + off);
  const float4 b = *(const float4*)(src + off + 4);
  short8 o;
  o[0] = f2b(a.x); o[1] = f2b(a.y); o[2] = f2b(a.z); o[3] = f2b(a.w);
  o[4] = f2b(b.x); o[5] = f2b(b.y); o[6] = f2b(b.z); o[7] = f2b(b.w);
  *(short8*)(dst + off) = o;
}

// ---------------------------------------------------------------------------
// f32->bf16 conversion of hidden (2M) + in_proj weights (4M): only what
// in_proj needs. 3072 blocks.
// ---------------------------------------------------------------------------
__global__ __launch_bounds__(256) void cvt_ab(
    const float* __restrict__ s0, bf16u* __restrict__ d0,
    const float* __restrict__ s1, bf16u* __restrict__ d1) {
  const size_t M1 = 1u << 20;
  size_t i = (size_t)(blockIdx.x * 256 + threadIdx.x) * 8;
  if (i < 2 * M1) cvt8(s0, d0, i);
  else if (i < 6 * M1) cvt8(s1, d1, i - 2 * M1);
}

// ---------------------------------------------------------------------------
// bf16 MFMA GEMM (r10-proven config):  C[m,n] = sum_k A[m][k+kbase]*B[n][k+kbase]
// Tile 128x64, BK=32, 256 threads (2x2 waves of 64x32), 36KB ring-3 LDS
// (4 blocks/CU). Single barrier/iter, reads-before-barrier, counted vmcnt
// distance-1. T1 XCD-chunked swizzle, M-fastest decode. grid.z = split-K
// slices; writes to C + z*zstrideC (plain stores only — deterministic).
// ---------------------------------------------------------------------------
template <typename OutT>
__global__ __launch_bounds__(256) void gemm_mfma(
    const bf16u* __restrict__ A, const bf16u* __restrict__ B,
    OutT* __restrict__ C, int M, int N, int Ksub, int lda, int ldb,
    size_t zstrideC) {
  __shared__ bf16u sA[3][128 * 32];   // 8KB / buffer
  __shared__ bf16u sB[3][64 * 32];    // 4KB / buffer
  const int t = threadIdx.x;
  const int lane = t & 63, wave = t >> 6;
  // T1 swizzle (requires nwg % 8 == 0)
  const int nwg = gridDim.x * gridDim.y;
  const int fid = blockIdx.y * gridDim.x + blockIdx.x;
  const int tile = (fid & 7) * (nwg >> 3) + (fid >> 3);
  const int bm = (tile % gridDim.y) * 128;
  const int bn = (tile / gridDim.y) * 64;
  const int wr = wave >> 1, wc = wave & 1;
  const int kbase = blockIdx.z * Ksub;
  OutT* Cz = C + (size_t)blockIdx.z * zstrideC;

  const int ra0 = bm + (t >> 2), ra1 = bm + 64 + (t >> 2);
  int rb0 = bn + (t >> 2);
  rb0 = rb0 < N ? rb0 : N - 1;
  const int kc = (((t & 3) ^ ((t >> 4) & 3))) * 8;

  const bf16u* Ap0 = A + (size_t)ra0 * lda + kbase + kc;
  const bf16u* Ap1 = A + (size_t)ra1 * lda + kbase + kc;
  const bf16u* Bp0 = B + (size_t)rb0 * ldb + kbase + kc;
  const int ldsoff = (wave * 64) * 8;

#define STAGE(buf, k0)                                   \
  do {                                                   \
    gload16(Ap0 + (k0), sA[buf] + ldsoff);               \
    gload16(Ap1 + (k0), sA[buf] + 2048 + ldsoff);        \
    gload16(Bp0 + (k0), sB[buf] + ldsoff);               \
  } while (0)

  const f32x4 zero = {0.f, 0.f, 0.f, 0.f};
  f32x4 acc[4][2];
#pragma unroll
  for (int m = 0; m < 4; ++m)
#pragma unroll
    for (int n = 0; n < 2; ++n) acc[m][n] = zero;

  const int ln15 = lane & 15, kq = lane >> 4;
  const int kswz = ((kq ^ ((ln15 >> 2) & 3))) * 8;
  const int nt = Ksub >> 5;

  STAGE(0, 0);
  STAGE(1, 32);
  int curb = 0;
  for (int it = 0; it < nt; ++it) {
    if (it + 2 < nt) {
      const int nb = (it + 2) % 3;
      STAGE(nb, (it + 2) * 32);
      asm volatile("s_waitcnt vmcnt(3)" ::: "memory");
    } else {
      asm volatile("s_waitcnt vmcnt(0)" ::: "memory");
    }
    const bf16u* pA = sA[curb];
    const bf16u* pB = sB[curb];
    short8 af[4], bfr[2];
#pragma unroll
    for (int m = 0; m < 4; ++m)
      af[m] = *(const short8*)&pA[(wr * 64 + m * 16 + ln15) * 32 + kswz];
#pragma unroll
    for (int n = 0; n < 2; ++n)
      bfr[n] = *(const short8*)&pB[(wc * 32 + n * 16 + ln15) * 32 + kswz];
    asm volatile("s_waitcnt lgkmcnt(0)" ::: "memory");
    __builtin_amdgcn_sched_barrier(0);
    __builtin_amdgcn_s_barrier();
    __builtin_amdgcn_s_setprio(1);
#pragma unroll
    for (int m = 0; m < 4; ++m)
#pragma unroll
      for (int n = 0; n < 2; ++n)
        acc[m][n] = __builtin_amdgcn_mfma_f32_16x16x32_bf16(af[m], bfr[n], acc[m][n], 0, 0, 0);
    __builtin_amdgcn_s_setprio(0);
    curb = (curb == 2) ? 0 : curb + 1;
  }
#undef STAGE

  const int rbase = bm + wr * 64, cbase = bn + wc * 32;
#pragma unroll
  for (int m = 0; m < 4; ++m) {
#pragma unroll
    for (int n = 0; n < 2; ++n) {
      const int col = cbase + n * 16 + ln15;
      if (col < N) {
#pragma unroll
        for (int r = 0; r < 4; ++r) {
          const int row = rbase + m * 16 + kq * 4 + r;
          stv(&Cz[(size_t)row * N + col], acc[m][n][r]);
        }
      }
    }
  }
}

// ---------------------------------------------------------------------------
// Combined BC + dt projection dispatch (r16-proven). 1152 blocks:
//   fid < 1024 : BC tile, T1 swizzle over exactly 1024, bf16 out to BCb.
//   fid >= 1024: dt tile (split-K=8), f32 partials to dtbuf + z*65536.
// ---------------------------------------------------------------------------
__global__ __launch_bounds__(256) void gemm_bc_dt(
    const bf16u* __restrict__ A, const bf16u* __restrict__ Wbc,
    const bf16u* __restrict__ Wdt, bf16u* __restrict__ BCb,
    float* __restrict__ dtbuf) {
  __shared__ bf16u sA[3][128 * 32];
  __shared__ bf16u sB[3][64 * 32];
  const int t = threadIdx.x;
  const int lane = t & 63, wave = t >> 6;
  const int fid = blockIdx.x;

  int bm, bn, kbase, nt, N, zdt = 0;
  const bf16u* Bw;
  bool isdt;
  if (fid < 1024) {
    isdt = false;
    const int tile = (fid & 7) * 128 + (fid >> 3);   // T1 over exactly 1024
    bm = (tile % 16) * 128;
    bn = (tile / 16) * 64;
    kbase = 0; nt = 64; N = 4096; Bw = Wbc;
  } else {
    isdt = true;
    const int did = fid - 1024;       // 0..127
    zdt = did >> 4;                   // split-K slice 0..7
    bm = (did & 15) * 128;
    bn = 0;
    kbase = zdt * 256; nt = 8; N = 32; Bw = Wdt;
  }
  const int wr = wave >> 1, wc = wave & 1;

  const int ra0 = bm + (t >> 2), ra1 = bm + 64 + (t >> 2);
  int rb0 = bn + (t >> 2);
  rb0 = rb0 < N ? rb0 : N - 1;
  const int kc = (((t & 3) ^ ((t >> 4) & 3))) * 8;

  const bf16u* Ap0 = A + (size_t)ra0 * 2048 + kbase + kc;
  const bf16u* Ap1 = A + (size_t)ra1 * 2048 + kbase + kc;
  const bf16u* Bp0 = Bw + (size_t)rb0 * 2048 + kbase + kc;
  const int ldsoff = (wave * 64) * 8;

#define STAGE(buf, k0)                                   \
  do {                                                   \
    gload16(Ap0 + (k0), sA[buf] + ldsoff);               \
    gload16(Ap1 + (k0), sA[buf] + 2048 + ldsoff);        \
    gload16(Bp0 + (k0), sB[buf] + ldsoff);               \
  } while (0)

  const f32x4 zero = {0.f, 0.f, 0.f, 0.f};
  f32x4 acc[4][2];
#pragma unroll
  for (int m = 0; m < 4; ++m)
#pragma unroll
    for (int n = 0; n < 2; ++n) acc[m][n] = zero;

  const int ln15 = lane & 15, kq = lane >> 4;
  const int kswz = ((kq ^ ((ln15 >> 2) & 3))) * 8;

  STAGE(0, 0);
  STAGE(1, 32);
  int curb = 0;
  for (int it = 0; it < nt; ++it) {
    if (it + 2 < nt) {
      const int nb = (it + 2) % 3;
      STAGE(nb, (it + 2) * 32);
      asm volatile("s_waitcnt vmcnt(3)" ::: "memory");
    } else {
      asm volatile("s_waitcnt vmcnt(0)" ::: "memory");
    }
    const bf16u* pA = sA[curb];
    const bf16u* pB = sB[curb];
    short8 af[4], bfr[2];
#pragma unroll
    for (int m = 0; m < 4; ++m)
      af[m] = *(const short8*)&pA[(wr * 64 + m * 16 + ln15) * 32 + kswz];
#pragma unroll
    for (int n = 0; n < 2; ++n)
      bfr[n] = *(const short8*)&pB[(wc * 32 + n * 16 + ln15) * 32 + kswz];
    asm volatile("s_waitcnt lgkmcnt(0)" ::: "memory");
    __builtin_amdgcn_sched_barrier(0);
    __builtin_amdgcn_s_barrier();
    __builtin_amdgcn_s_setprio(1);
#pragma unroll
    for (int m = 0; m < 4; ++m)
#pragma unroll
      for (int n = 0; n < 2; ++n)
        acc[m][n] = __builtin_amdgcn_mfma_f32_16x16x32_bf16(af[m], bfr[n], acc[m][n], 0, 0, 0);
    __builtin_amdgcn_s_setprio(0);
    curb = (curb == 2) ? 0 : curb + 1;
  }
#undef STAGE

  const int rbase = bm + wr * 64, cbase = bn + wc * 32;
  if (!isdt) {
#pragma unroll
    for (int m = 0; m < 4; ++m) {
#pragma unroll
      for (int n = 0; n < 2; ++n) {
        const int col = cbase + n * 16 + ln15;
#pragma unroll
        for (int r = 0; r < 4; ++r) {
          const int row = rbase + m * 16 + kq * 4 + r;
          BCb[(size_t)row * 4096 + col] = f2b(acc[m][n][r]);
        }
      }
    }
  } else {
    float* Cz = dtbuf + (size_t)zdt * 65536;
#pragma unroll
    for (int m = 0; m < 4; ++m) {
#pragma unroll
      for (int n = 0; n < 2; ++n) {
        const int col = cbase + n * 16 + ln15;
        if (col < 32) {
#pragma unroll
          for (int r = 0; r < 4; ++r) {
            const int row = rbase + m * 16 + kq * 4 + r;
            Cz[(size_t)row * 32 + col] = acc[m][n][r];
          }
        }
      }
    }
  }
}

// ---------------------------------------------------------------------------
// out = a + b (f32), 4 elems/thread
// ---------------------------------------------------------------------------
__global__ __launch_bounds__(256) void add_f32(const float* __restrict__ a,
                                               const float* __restrict__ b,
                                               float* __restrict__ o, int n) {
  const int i = (blockIdx.x * 256 + threadIdx.x) * 4;
  if (i >= n) return;
  const float4 x = *(const float4*)(a + i);
  const float4 y = *(const float4*)(b + i);
  *(float4*)(o + i) = make_float4(x.x + y.x, x.y + y.y, x.z + y.z, x.w + y.w);
}

// ---------------------------------------------------------------------------
// Combined depthwise causal conv (width 4, bias, SiLU) + f32->bf16 cvt of
// the remaining weights (B_w 4M | C_w 4M | out_proj 2M | dt_w 64K).
// Blocks [0,2048): conv. Blocks [2048,7200): cvt. Disjoint outputs; the
// weight conversions ride the conv dispatch (both precede gemm_bc_dt).
// ---------------------------------------------------------------------------
__global__ __launch_bounds__(256) void conv_cvt(
    const bf16u* __restrict__ xzb, const float* __restrict__ cw,
    const float* __restrict__ cb, bf16u* __restrict__ xcb,
    const float* __restrict__ Bw, bf16u* __restrict__ dB,
    const float* __restrict__ Cw, bf16u* __restrict__ dC,
    const float* __restrict__ Ow, bf16u* __restrict__ dO,
    const float* __restrict__ Dw, bf16u* __restrict__ dD) {
  const size_t M1 = 1u << 20;
  if (blockIdx.x >= 2048) {
    const size_t i = (size_t)((blockIdx.x - 2048) * 256 + threadIdx.x) * 8;
    if (i < 4 * M1) cvt8(Bw, dB, i);
    else if (i < 8 * M1) cvt8(Cw, dC, i - 4 * M1);
    else if (i < 10 * M1) cvt8(Ow, dO, i - 8 * M1);
    else if (i < 10 * M1 + 65536) cvt8(Dw, dD, i - 10 * M1);
    return;
  }
  const int i = blockIdx.x * 256 + threadIdx.x;  // 0..512K
  const int c8 = (i & 255) * 8;
  const int tok = i >> 8;
  const int l = tok & (SEQLEN - 1);
  const bf16u* xp = xzb + (size_t)tok * (2 * DINNER) + c8;
  const short8 zer = {0, 0, 0, 0, 0, 0, 0, 0};
  const short8 x0 = *(const short8*)xp;
  const short8 x1 = (l >= 1) ? *(const short8*)(xp - 1 * (2 * DINNER)) : zer;
  const short8 x2 = (l >= 2) ? *(const short8*)(xp - 2 * (2 * DINNER)) : zer;
  const short8 x3 = (l >= 3) ? *(const short8*)(xp - 3 * (2 * DINNER)) : zer;
  short8 ob;
#pragma unroll
  for (int j = 0; j < 8; ++j) {
    const float4 w = *(const float4*)(cw + (c8 + j) * 4);
    float acc = cb[c8 + j] + w.w * b2f(x0[j]);
    acc += w.z * b2f(x1[j]);
    acc += w.y * b2f(x2[j]);
    acc += w.x * b2f(x3[j]);
    const float s = acc / (1.f + __expf(-acc));
    ob[j] = (short)f2b(s);
  }
  *(short8*)(xcb + (size_t)tok * DINNER + c8) = ob;
}

// ---------------------------------------------------------------------------
// Chunked SSD, stage 1 (per chunk): dt softplus (fused from 8 split-K
// partials), decay cumsum, G=C@B^T masked -> P, Y_intra = P@X (bf16 out),
// S = X^T diag(w) B. One block per (b,h,c).
// BCb [NTOK,4096]: cols [0,2048)=B, [2048,4096)=C.
// ---------------------------------------------------------------------------
__global__ __launch_bounds__(256) void chunk_intra(
    const bf16u* __restrict__ xcb, const bf16u* __restrict__ BCb,
    const float* __restrict__ dtp8, const float* __restrict__ dt_b,
    const float* __restrict__ A_log,
    bf16u* __restrict__ ybb, float* __restrict__ Sbuf,
    float* __restrict__ rbuf, float* __restrict__ lambuf) {
  __shared__ bf16u sC[64 * LDP], sB[64 * LDP], sXT[64 * LDP];
  __shared__ bf16u sWBT[64 * LDP], sP[64 * LDP];
  __shared__ float sS[64], sDt[64], sW[64];

  const int blk = blockIdx.x;
  const int bh = blk >> 4, c = blk & (NCHUNK - 1);
  const int b = bh >> 5, h = bh & (NHEADS - 1);
  const int t = threadIdx.x, lane = t & 63, wave = t >> 6;
  const int t0 = b * SEQLEN + c * 64;
  const size_t rowbase = (size_t)t0 * DINNER + h * 64;        // x
  const size_t rowBC = (size_t)t0 * 4096 + h * 64;            // fused B/C

  // ---- P0: staging + dt softplus + decay scan ----
  if (wave == 0) {
    const size_t di = (size_t)(t0 + lane) * NHEADS + h;
    float dr = dt_b[h];
#pragma unroll
    for (int k = 0; k < 8; ++k) dr += dtp8[di + (size_t)k * 65536];
    const float dtv = (dr > 20.f) ? dr : log1pf(__expf(dr));
    const float Ah = -__expf(A_log[h]);
    float s = Ah * dtv;
#pragma unroll
    for (int off = 1; off < 64; off <<= 1) {
      const float o = __shfl_up(s, off);
      if (lane >= off) s += o;
    }
    const float stot = __shfl(s, 63);
    sS[lane] = s;
    sDt[lane] = dtv;
    sW[lane] = __expf(stot - s) * dtv;
    rbuf[(size_t)blk * 64 + lane] = __expf(s);
    if (lane == 0) lambuf[blk] = __expf(stot);
  } else if (wave == 1) {
#pragma unroll
    for (int it = 0; it < 8; ++it) {
      const int slot = it * 64 + lane;
      const int r = slot >> 3, c8 = (slot & 7) * 8;
      *(short8*)&sC[r * LDP + c8] =
          *(const short8*)&BCb[rowBC + 2048 + (size_t)r * 4096 + c8];
    }
  } else if (wave == 2) {
#pragma unroll
    for (int it = 0; it < 8; ++it) {
      const int slot = it * 64 + lane;
      const int r = slot >> 3, c8 = (slot & 7) * 8;
      *(short8*)&sB[r * LDP + c8] =
          *(const short8*)&BCb[rowBC + (size_t)r * 4096 + c8];
    }
  } else {
#pragma unroll
    for (int it = 0; it < 8; ++it) {
      const int slot = it * 64 + lane;
      const int j = slot >> 3, p0 = (slot & 7) * 8;
      const short8 v = *(const short8*)&xcb[rowbase + (size_t)j * DINNER + p0];
#pragma unroll
      for (int k = 0; k < 8; ++k) sXT[(p0 + k) * LDP + j] = v[k];
    }
  }
  __syncthreads();

  // ---- P1: WBT[n][j] = w_j * B[j][n]; G mfma + mask -> P ----
  {
    const int j = t >> 2, n0 = (t & 3) * 16;
    const float wj = sW[j];
#pragma unroll
    for (int k = 0; k < 16; ++k)
      sWBT[(n0 + k) * LDP + j] = f2b(wj * b2f(sB[j * LDP + n0 + k]));
  }
  const int ln15 = lane & 15, kq = lane >> 4;
  const int i0 = wave * 16;
  const f32x4 zero = {0.f, 0.f, 0.f, 0.f};
  {
    f32x4 g[4];
#pragma unroll
    for (int jf = 0; jf < 4; ++jf) g[jf] = zero;
#pragma unroll
    for (int k0 = 0; k0 < 64; k0 += 32) {
      const short8 a = *(const short8*)&sC[(i0 + ln15) * LDP + k0 + kq * 8];
#pragma unroll
      for (int jf = 0; jf < 4; ++jf) {
        const short8 bb = *(const short8*)&sB[(jf * 16 + ln15) * LDP + k0 + kq * 8];
        g[jf] = __builtin_amdgcn_mfma_f32_16x16x32_bf16(a, bb, g[jf], 0, 0, 0);
      }
    }
#pragma unroll
    for (int jf = 0; jf < 4; ++jf) {
      const int j = jf * 16 + ln15;
      const float sj = sS[j], dtj = sDt[j];
#pragma unroll
      for (int r = 0; r < 4; ++r) {
        const int i = i0 + kq * 4 + r;
        const float v = (j <= i) ? g[jf][r] * __expf(sS[i] - sj) * dtj : 0.f;
        sP[i * LDP + j] = f2b(v);
      }
    }
  }
  __syncthreads();

  // ---- P2: Y_intra = P @ XT^T ; S = XT @ WBT^T ----
  f32x4 yi[4], ss[4];
#pragma unroll
  for (int f = 0; f < 4; ++f) { yi[f] = zero; ss[f] = zero; }
#pragma unroll
  for (int k0 = 0; k0 < 64; k0 += 32) {
    const short8 ap = *(const short8*)&sP[(i0 + ln15) * LDP + k0 + kq * 8];
    const short8 ax = *(const short8*)&sXT[(i0 + ln15) * LDP + k0 + kq * 8];
#pragma unroll
    for (int f = 0; f < 4; ++f) {
      const short8 bx = *(const short8*)&sXT[(f * 16 + ln15) * LDP + k0 + kq * 8];
      const short8 bw = *(const short8*)&sWBT[(f * 16 + ln15) * LDP + k0 + kq * 8];
      yi[f] = __builtin_amdgcn_mfma_f32_16x16x32_bf16(ap, bx, yi[f], 0, 0, 0);
      ss[f] = __builtin_amdgcn_mfma_f32_16x16x32_bf16(ax, bw, ss[f], 0, 0, 0);
    }
  }
  bf16u* yb = ybb + (size_t)blk * 4096;
  float* sb = Sbuf + (size_t)blk * 4096;
#pragma unroll
  for (int f = 0; f < 4; ++f) {
#pragma unroll
    for (int r = 0; r < 4; ++r) {
      const int row = i0 + kq * 4 + r;
      const int col = f * 16 + ln15;
      yb[row * 64 + col] = f2b(yi[f][r]);
      sb[row * 64 + col] = ss[f][r];
    }
  }
}

// ---------------------------------------------------------------------------
// Chunked SSD, stage 2: inter-chunk state scan (16 steps, scalar decay).
// ---------------------------------------------------------------------------
__global__ __launch_bounds__(256) void chunk_scan(
    const float* __restrict__ Sbuf, const float* __restrict__ lambuf,
    bf16u* __restrict__ Hprevb, float* __restrict__ hf) {
  const int bh = blockIdx.x;
  const int t = threadIdx.x;
  const int e0 = t * 16;
  float H[16];
#pragma unroll
  for (int j = 0; j < 16; ++j) H[j] = 0.f;

  float4 cur[4];
  float lam;
  {
    const float4* sp = (const float4*)(Sbuf + (size_t)(bh * NCHUNK) * 4096 + e0);
#pragma unroll
    for (int q = 0; q < 4; ++q) cur[q] = sp[q];
    lam = lambuf[bh * NCHUNK];
  }
  for (int c = 0; c < NCHUNK; ++c) {
    float4 nxt[4];
    float lamn = 0.f;
    if (c < NCHUNK - 1) {
      const float4* sp = (const float4*)(Sbuf + (size_t)(bh * NCHUNK + c + 1) * 4096 + e0);
#pragma unroll
      for (int q = 0; q < 4; ++q) nxt[q] = sp[q];
      lamn = lambuf[bh * NCHUNK + c + 1];
    }
    short8 o0, o1;
#pragma unroll
    for (int j = 0; j < 8; ++j) o0[j] = (short)f2b(H[j]);
#pragma unroll
    for (int j = 0; j < 8; ++j) o1[j] = (short)f2b(H[8 + j]);
    *(short8*)&Hprevb[(size_t)(bh * NCHUNK + c) * 4096 + e0] = o0;
    *(short8*)&Hprevb[(size_t)(bh * NCHUNK + c) * 4096 + e0 + 8] = o1;
#pragma unroll
    for (int q = 0; q < 4; ++q) {
      H[q * 4 + 0] = lam * H[q * 4 + 0] + cur[q].x;
      H[q * 4 + 1] = lam * H[q * 4 + 1] + cur[q].y;
      H[q * 4 + 2] = lam * H[q * 4 + 2] + cur[q].z;
      H[q * 4 + 3] = lam * H[q * 4 + 3] + cur[q].w;
    }
#pragma unroll
    for (int q = 0; q < 4; ++q) cur[q] = nxt[q];
    lam = lamn;
  }
  float* hp = hf + (size_t)bh * 4096 + e0;
#pragma unroll
  for (int q = 0; q < 4; ++q)
    *(float4*)(hp + q * 4) =
        make_float4(H[q * 4], H[q * 4 + 1], H[q * 4 + 2], H[q * 4 + 3]);
}

// ---------------------------------------------------------------------------
// Chunked SSD, stage 3 (per chunk): Y = Y_intra + r_i * C @ Hprev^T + D*x.
// ---------------------------------------------------------------------------
__global__ __launch_bounds__(256) void chunk_inter(
    const bf16u* __restrict__ BCb, const bf16u* __restrict__ Hprevb,
    const bf16u* __restrict__ xcb, const bf16u* __restrict__ ybb,
    const float* __restrict__ rbuf, const float* __restrict__ Dvec,
    bf16u* __restrict__ yout) {
  __shared__ bf16u sC[64 * LDP], sH[64 * LDP];
  __shared__ float sR[64];
  const int blk = blockIdx.x;
  const int bh = blk >> 4, c = blk & (NCHUNK - 1);
  const int b = bh >> 5, h = bh & (NHEADS - 1);
  const int t = threadIdx.x, lane = t & 63, wave = t >> 6;
  const int t0 = b * SEQLEN + c * 64;
  const size_t rowbase = (size_t)t0 * DINNER + h * 64;
  const size_t rowBC = (size_t)t0 * 4096 + h * 64;

#pragma unroll
  for (int it = 0; it < 2; ++it) {
    const int slot = it * 256 + t;          // 0..511
    const int r = slot >> 3, c8 = (slot & 7) * 8;
    *(short8*)&sC[r * LDP + c8] =
        *(const short8*)&BCb[rowBC + 2048 + (size_t)r * 4096 + c8];
    *(short8*)&sH[r * LDP + c8] =
        *(const short8*)&Hprevb[(size_t)blk * 4096 + slot * 8];
  }
  if (t < 64) sR[t] = rbuf[(size_t)blk * 64 + t];
  __syncthreads();

  const int ln15 = lane & 15, kq = lane >> 4;
  const int i0 = wave * 16;
  const f32x4 zero = {0.f, 0.f, 0.f, 0.f};
  f32x4 acc[4];
#pragma unroll
  for (int f = 0; f < 4; ++f) acc[f] = zero;
#pragma unroll
  for (int k0 = 0; k0 < 64; k0 += 32) {
    const short8 a = *(const short8*)&sC[(i0 + ln15) * LDP + k0 + kq * 8];
#pragma unroll
    for (int f = 0; f < 4; ++f) {
      const short8 bh8 = *(const short8*)&sH[(f * 16 + ln15) * LDP + k0 + kq * 8];
      acc[f] = __builtin_amdgcn_mfma_f32_16x16x32_bf16(a, bh8, acc[f], 0, 0, 0);
    }
  }
  const float Dh = Dvec[h];
  const bf16u* yb = ybb + (size_t)blk * 4096;
#pragma unroll
  for (int f = 0; f < 4; ++f) {
    const int p = f * 16 + ln15;
#pragma unroll
    for (int r = 0; r < 4; ++r) {
      const int i = i0 + kq * 4 + r;
      const float xv = b2f((short)xcb[rowbase + (size_t)i * DINNER + p]);
      const float y = b2f((short)yb[i * 64 + p]) + sR[i] * acc[f][r] + Dh * xv;
      yout[rowbase + (size_t)i * DINNER + p] = f2b(y);
    }
  }
}

// ---------------------------------------------------------------------------
// LayerNorm(2048) + SiLU(z) gate. bf16 y/z in, bf16 out. One block per token.
// ---------------------------------------------------------------------------
__global__ __launch_bounds__(256) void ln_gate(
    const bf16u* __restrict__ y, const bf16u* __restrict__ xzb,
    const float* __restrict__ lnw, const float* __restrict__ lnb,
    bf16u* __restrict__ out) {
  const int tok = blockIdx.x;
  const int t = threadIdx.x;
  const short8 yv8 = *(const short8*)(y + (size_t)tok * DINNER + t * 8);
  const short8 zv8 = *(const short8*)(xzb + (size_t)tok * (2 * DINNER) + DINNER + t * 8);
  float v[8];
  float s = 0.f, s2 = 0.f;
#pragma unroll
  for (int j = 0; j < 8; ++j) {
    v[j] = b2f(yv8[j]);
    s += v[j];
    s2 += v[j] * v[j];
  }
#pragma unroll
  for (int off = 32; off > 0; off >>= 1) {
    s += __shfl_down(s, off);
    s2 += __shfl_down(s2, off);
  }
  __shared__ float ws[4], ws2[4];
  const int wid = t >> 6;
  if ((t & 63) == 0) { ws[wid] = s; ws2[wid] = s2; }
  __syncthreads();
  const float mean = (ws[0] + ws[1] + ws[2] + ws[3]) * (1.f / DINNER);
  const float m2 = (ws2[0] + ws2[1] + ws2[2] + ws2[3]) * (1.f / DINNER);
  const float rstd = rsqrtf(m2 - mean * mean + 1e-5f);
  const float4 w0 = *(const float4*)(lnw + t * 8);
  const float4 w1 = *(const float4*)(lnw + t * 8 + 4);
  const float4 b0 = *(const float4*)(lnb + t * 8);
  const float4 b1 = *(const float4*)(lnb + t * 8 + 4);
  const float wv[8] = {w0.x, w0.y, w0.z, w0.w, w1.x, w1.y, w1.z, w1.w};
  const float bv[8] = {b0.x, b0.y, b0.z, b0.w, b1.x, b1.y, b1.z, b1.w};
  short8 o;
#pragma unroll
  for (int j = 0; j < 8; ++j) {
    const float zn = b2f(zv8[j]);
    const float gate = zn / (1.f + __expf(-zn));
    o[j] = (short)f2b(((v[j] - mean) * rstd * wv[j] + bv[j]) * gate);
  }
  *(short8*)(out + (size_t)tok * DINNER + t * 8) = o;
}

// ---------------------------------------------------------------------------
extern "C" void kernel_launch(void* const* d_in, const int* in_sizes, int n_in,
                              void* d_out, int out_size, void* d_ws, size_t ws_size,
                              hipStream_t stream) {
  const float* hidden = (const float*)d_in[0];
  const float* in_proj_w = (const float*)d_in[1];
  const float* conv_w = (const float*)d_in[2];
  const float* conv_b = (const float*)d_in[3];
  const float* A_log = (const float*)d_in[4];
  const float* dt_w = (const float*)d_in[5];
  const float* dt_b = (const float*)d_in[6];
  const float* B_w = (const float*)d_in[7];
  const float* C_w = (const float*)d_in[8];
  const float* Dv = (const float*)d_in[9];
  const float* ln_w = (const float*)d_in[10];
  const float* ln_b = (const float*)d_in[11];
  const float* out_proj_w = (const float*)d_in[12];

  float* out = (float*)d_out;
  float* f = (float*)d_ws;
  const size_t M1 = 1u << 20;

  // workspace layout (float-offset units) — r12/r15 layout (known good):
  bf16u* xzb    = (bf16u*)(f + 0);            // [0,4M)   xz bf16 (8M elems)
  bf16u* xcb    = (bf16u*)(f + 4 * M1);       // [4M,6M)  conv out bf16
  bf16u* BCb    = (bf16u*)(f + 6 * M1);       // [6M,10M) fused B/C proj out
  bf16u* wBCb   = (bf16u*)(f + 10 * M1);      // [10M,14M) fused B/C weights (dead after BC gemm)
  bf16u* ybb    = (bf16u*)(f + 10 * M1);      // [10M,12M) y_intra bf16 (after wBCb dead)
  float* outp   = f + 6 * M1;                 // [6M,10M) 2 split-K partials (after BCb dead)
  bf16u* wInb   = (bf16u*)(f + 14 * M1);      // [14M,16M) (dead after in_proj)
  bf16u* hiddenb= (bf16u*)(f + 16 * M1);      // [16M,17M) (dead after in_proj)
  bf16u* wdtb   = (bf16u*)(f + 17 * M1);      // [17M,+32K) (dead after bc_dt gemm)
  float* Sbuf   = f + 14 * M1;                // [14M,18M) (after wInb/hiddenb/wdtb dead)
  bf16u* ygb    = (bf16u*)(f + 14 * M1);      // [14M,16M) (after Sbuf dead)
  bf16u* yscb   = (bf16u*)(f + 16 * M1);      // [16M,18M) (after Sbuf dead)
  bf16u* Hprevb = (bf16u*)(f + 18 * M1);      // [18M,20M)
  bf16u* wOb    = (bf16u*)(f + 20 * M1);      // [20M,21M)
  float* dtbuf  = f + 21 * M1;                // [21M,+512K) 8 split-K partials
  float* rbuf   = f + 21 * M1 + 524288;       // [+64K]
  float* lambuf = f + 21 * M1 + 589824;       // [+1K]

  float* hf = out + OUT_ELEMS;

  // 0. convert only what in_proj needs (hidden + in_proj weights)
  cvt_ab<<<3072, 256, 0, stream>>>(hidden, hiddenb, in_proj_w, wInb);

  // 1. xz = hidden @ in_proj_w^T  [2048 x 4096], K=1024  (bf16 out)
  gemm_mfma<bf16u><<<dim3(64, 16, 1), 256, 0, stream>>>(
      hiddenb, wInb, xzb, NTOK, 2 * DINNER, DMODEL, DMODEL, DMODEL, 0);
  // 2. conv + SiLU -> xcb (bf16)  +  cvt of B/C/out/dt weights (rides along)
  conv_cvt<<<7200, 256, 0, stream>>>(xzb, conv_w, conv_b, xcb,
                                     B_w, wBCb, C_w, wBCb + 4 * M1,
                                     out_proj_w, wOb, dt_w, wdtb);
  // 3. combined: fused B/C projection (1024 tiles) + dt split-K=8 (128 tiles)
  gemm_bc_dt<<<1152, 256, 0, stream>>>(xcb, wBCb, wdtb, BCb, dtbuf);
  // 4. per-chunk intra + states (dt softplus fused in)
  chunk_intra<<<BATCH * NHEADS * NCHUNK, 256, 0, stream>>>(
      xcb, BCb, dtbuf, dt_b, A_log, ybb, Sbuf, rbuf, lambuf);
  // 5. inter-chunk scan (also writes h_final)
  chunk_scan<<<BATCH * NHEADS, 256, 0, stream>>>(Sbuf, lambuf, Hprevb, hf);
  // 6. combine -> y (bf16)
  chunk_inter<<<BATCH * NHEADS * NCHUNK, 256, 0, stream>>>(
      BCb, Hprevb, xcb, ybb, rbuf, Dv, yscb);
  // 7. LN + gate -> ygb (bf16)
  ln_gate<<<NTOK, 256, 0, stream>>>(yscb, xzb, ln_w, ln_b, ygb);
  // 8. out = yg @ out_proj_w^T  [2048 x 1024], K=2048, split-K=2 (f32 partials)
  gemm_mfma<float><<<dim3(16, 16, 2), 256, 0, stream>>>(
      ygb, wOb, outp, NTOK, DMODEL, DINNER / 2, DINNER, DINNER,
      (size_t)2 * M1);
  add_f32<<<2048, 256, 0, stream>>>(outp, outp + 2 * M1, out, OUT_ELEMS);
}